// Round 1
// baseline (1085.591 us; speedup 1.0000x reference)
//
#include <hip/hip_runtime.h>
#include <hip/hip_bf16.h>
#include <math.h>

// GATNet: 2-layer GAT, N=50000 nodes, E=800000 edges (+N self loops),
// F_IN=256, HID=64, NCLS=40, HEADS=8.
// Pipeline: CSR-by-dst build (hist/scan/scatter), fp32 tiled GEMMs,
// wave-per-node attention + aggregation (no atomics in aggregation:
// softmax normalization folded into the per-node reduction since
// sum(alpha*h) = sum(p*h)/sum(p), identical to the max-shifted reference).

#define NEG_SLOPE 0.2f

// ---------------- CSR build ----------------

__global__ __launch_bounds__(256) void hist_k(const int* __restrict__ ei, int* __restrict__ deg,
                                              int E, int Nn) {
    int e = blockIdx.x * 256 + threadIdx.x;
    int ET = E + Nn;
    if (e >= ET) return;
    int d = (e < E) ? ei[E + e] : (e - E);   // ei[1] row = dst
    atomicAdd(&deg[d], 1);
}

__global__ __launch_bounds__(1024) void scan_k(const int* __restrict__ deg, int* __restrict__ rowstart,
                                               int n, int total) {
    __shared__ int smem[1024];
    __shared__ int carry;
    int t = threadIdx.x;
    if (t == 0) carry = 0;
    __syncthreads();
    for (int base = 0; base < n; base += 1024) {
        int v = (base + t < n) ? deg[base + t] : 0;
        smem[t] = v;
        __syncthreads();
        for (int off = 1; off < 1024; off <<= 1) {
            int u = (t >= off) ? smem[t - off] : 0;
            __syncthreads();
            smem[t] += u;
            __syncthreads();
        }
        int inc = smem[t];
        int tot = smem[1023];
        int c = carry;
        if (base + t < n) rowstart[base + t] = c + inc - v;  // exclusive
        __syncthreads();
        if (t == 0) carry = c + tot;
        __syncthreads();
    }
    if (t == 0) rowstart[n] = total;
}

__global__ __launch_bounds__(256) void scatter_k(const int* __restrict__ ei,
                                                 const int* __restrict__ rowstart,
                                                 int* __restrict__ cursor,
                                                 int* __restrict__ srcs, int E, int Nn) {
    int e = blockIdx.x * 256 + threadIdx.x;
    int ET = E + Nn;
    if (e >= ET) return;
    int s, d;
    if (e < E) { s = ei[e]; d = ei[E + e]; }
    else       { s = e - E; d = e - E; }
    int pos = atomicAdd(&cursor[d], 1);
    srcs[rowstart[d] + pos] = s;
}

// ---------------- fp32 tiled GEMM: C[M,Nc] = A[M,K] * B[Nc,K]^T ----------------

__global__ __launch_bounds__(256) void gemm_nt(const float* __restrict__ A, const float* __restrict__ B,
                                               float* __restrict__ C, int M, int Nc, int K) {
    __shared__ float As[16][65];
    __shared__ float Bs[16][65];
    const int t  = threadIdx.x;
    const int tx = t & 15, ty = t >> 4;
    const int m0 = blockIdx.x * 64, n0 = blockIdx.y * 64;
    const int lm = t >> 2;           // 0..63
    const int lk = (t & 3) << 2;     // 0,4,8,12
    float acc[4][4] = {};
    for (int kt = 0; kt < K; kt += 16) {
        int gm = m0 + lm;
        float4 av;
        if (gm < M) av = *reinterpret_cast<const float4*>(A + (size_t)gm * K + kt + lk);
        else        av = make_float4(0.f, 0.f, 0.f, 0.f);
        As[lk + 0][lm] = av.x; As[lk + 1][lm] = av.y; As[lk + 2][lm] = av.z; As[lk + 3][lm] = av.w;
        float4 bv = *reinterpret_cast<const float4*>(B + (size_t)(n0 + lm) * K + kt + lk);
        Bs[lk + 0][lm] = bv.x; Bs[lk + 1][lm] = bv.y; Bs[lk + 2][lm] = bv.z; Bs[lk + 3][lm] = bv.w;
        __syncthreads();
#pragma unroll
        for (int kk = 0; kk < 16; kk++) {
            float a[4], b[4];
#pragma unroll
            for (int i = 0; i < 4; i++) a[i] = As[kk][ty * 4 + i];
#pragma unroll
            for (int j = 0; j < 4; j++) b[j] = Bs[kk][tx * 4 + j];
#pragma unroll
            for (int i = 0; i < 4; i++)
#pragma unroll
                for (int j = 0; j < 4; j++) acc[i][j] = fmaf(a[i], b[j], acc[i][j]);
        }
        __syncthreads();
    }
#pragma unroll
    for (int i = 0; i < 4; i++) {
        int gm = m0 + ty * 4 + i;
        if (gm < M) {
#pragma unroll
            for (int j = 0; j < 4; j++) C[(size_t)gm * Nc + n0 + tx * 4 + j] = acc[i][j];
        }
    }
}

// ---------------- layer-1 attention logits (wave per node, 8 heads x 64 chan) ----------------

__global__ __launch_bounds__(256) void att1_k(const float* __restrict__ h1,
                                              const float* __restrict__ a0s, const float* __restrict__ a0d,
                                              float* __restrict__ as1, float* __restrict__ ad1, int Nn) {
    int wave = threadIdx.x >> 6, lane = threadIdx.x & 63;
    int n = blockIdx.x * 4 + wave;
    if (n >= Nn) return;
    const float* hr = h1 + (size_t)n * 512;
#pragma unroll
    for (int k = 0; k < 8; k++) {
        float v  = hr[k * 64 + lane];
        float s1 = v * a0s[k * 64 + lane];
        float s2 = v * a0d[k * 64 + lane];
        for (int off = 32; off > 0; off >>= 1) {
            s1 += __shfl_down(s1, off, 64);
            s2 += __shfl_down(s2, off, 64);
        }
        if (lane == 0) { as1[n * 8 + k] = s1; ad1[n * 8 + k] = s2; }
    }
}

// ---------------- layer-1 aggregation (wave per dst node) ----------------

__global__ __launch_bounds__(256) void agg1_k(const float* __restrict__ h1,
                                              const float* __restrict__ as1, const float* __restrict__ ad1,
                                              const int* __restrict__ srcs, const int* __restrict__ rowstart,
                                              const float* __restrict__ b0, float* __restrict__ x1, int Nn) {
    int wave = threadIdx.x >> 6, lane = threadIdx.x & 63;
    int n = blockIdx.x * 4 + wave;
    if (n >= Nn) return;
    float adl[8];
#pragma unroll
    for (int h = 0; h < 8; h++) adl[h] = ad1[n * 8 + h];
    float acc[8] = {0, 0, 0, 0, 0, 0, 0, 0};
    float ds[8]  = {0, 0, 0, 0, 0, 0, 0, 0};
    int beg = rowstart[n], end = rowstart[n + 1];
    for (int i = beg; i < end; i++) {
        int s = srcs[i];
        const float* hs = h1 + (size_t)s * 512;
        float p[8];
#pragma unroll
        for (int h = 0; h < 8; h++) {
            float e = as1[s * 8 + h] + adl[h];
            e = (e > 0.f) ? e : NEG_SLOPE * e;
            p[h] = __expf(e);
            ds[h] += p[h];
        }
#pragma unroll
        for (int k = 0; k < 8; k++) acc[k] = fmaf(p[k], hs[k * 64 + lane], acc[k]);
    }
    float v = 0.f;
#pragma unroll
    for (int k = 0; k < 8; k++) v += acc[k] / (ds[k] + 1e-16f);
    v = v * 0.125f + b0[lane];
    x1[(size_t)n * 64 + lane] = (v > 0.f) ? v : 0.f;
}

// ---------------- layer-2 attention logits (thread per node*head, dot40) ----------------

__global__ __launch_bounds__(256) void att2_k(const float* __restrict__ h2,
                                              const float* __restrict__ a2s, const float* __restrict__ a2d,
                                              float* __restrict__ as2, float* __restrict__ ad2, int Nn) {
    int t = blockIdx.x * 256 + threadIdx.x;
    if (t >= Nn * 8) return;
    int n = t >> 3, h = t & 7;
    const float* hr = h2 + (size_t)n * 320 + h * 40;
    const float* sv = a2s + h * 40;
    const float* dv = a2d + h * 40;
    float s1 = 0.f, s2 = 0.f;
#pragma unroll
    for (int j = 0; j < 40; j++) {
        float v = hr[j];
        s1 = fmaf(v, sv[j], s1);
        s2 = fmaf(v, dv[j], s2);
    }
    as2[t] = s1;
    ad2[t] = s2;
}

// ---------------- layer-2 aggregation + head-mean + bias + log_softmax ----------------

__global__ __launch_bounds__(256) void agg2_k(const float* __restrict__ h2,
                                              const float* __restrict__ as2, const float* __restrict__ ad2,
                                              const int* __restrict__ srcs, const int* __restrict__ rowstart,
                                              const float* __restrict__ b2, float* __restrict__ out, int Nn) {
    __shared__ float smem[4][320];
    int wave = threadIdx.x >> 6, lane = threadIdx.x & 63;
    int n = blockIdx.x * 4 + wave;
    bool active = (n < Nn);
    float acc[5] = {0, 0, 0, 0, 0};
    float ds[8]  = {0, 0, 0, 0, 0, 0, 0, 0};
    int hk[5];
#pragma unroll
    for (int k = 0; k < 5; k++) hk[k] = (k * 64 + lane) / 40;
    if (active) {
        float adl[8];
#pragma unroll
        for (int h = 0; h < 8; h++) adl[h] = ad2[n * 8 + h];
        int beg = rowstart[n], end = rowstart[n + 1];
        for (int i = beg; i < end; i++) {
            int s = srcs[i];
            const float* hs = h2 + (size_t)s * 320;
            float p[8];
#pragma unroll
            for (int h = 0; h < 8; h++) {
                float e = as2[s * 8 + h] + adl[h];
                e = (e > 0.f) ? e : NEG_SLOPE * e;
                p[h] = __expf(e);
                ds[h] += p[h];
            }
#pragma unroll
            for (int k = 0; k < 5; k++) acc[k] = fmaf(p[hk[k]], hs[k * 64 + lane], acc[k]);
        }
#pragma unroll
        for (int k = 0; k < 5; k++) smem[wave][k * 64 + lane] = acc[k] / (ds[hk[k]] + 1e-16f);
    }
    __syncthreads();
    if (active) {
        float v;
        if (lane < 40) {
            float ssum = 0.f;
#pragma unroll
            for (int h = 0; h < 8; h++) ssum += smem[wave][h * 40 + lane];
            v = ssum * 0.125f + b2[lane];
        } else {
            v = -INFINITY;
        }
        float m = v;
        for (int off = 32; off > 0; off >>= 1) m = fmaxf(m, __shfl_xor(m, off, 64));
        float ex = (lane < 40) ? __expf(v - m) : 0.f;
        float se = ex;
        for (int off = 32; off > 0; off >>= 1) se += __shfl_xor(se, off, 64);
        if (lane < 40) out[(size_t)n * 40 + lane] = v - m - __logf(se);
    }
}

// ---------------- launch ----------------

extern "C" void kernel_launch(void* const* d_in, const int* in_sizes, int n_in,
                              void* d_out, int out_size, void* d_ws, size_t ws_size,
                              hipStream_t stream) {
    const float* x   = (const float*)d_in[0];
    const int*   ei  = (const int*)d_in[1];
    // d_in[2] edge_attr: unused by GATConv
    const float* W0  = (const float*)d_in[3];
    const float* a0s = (const float*)d_in[4];
    const float* a0d = (const float*)d_in[5];
    const float* b0  = (const float*)d_in[6];
    const float* W2  = (const float*)d_in[7];
    const float* a2s = (const float*)d_in[8];
    const float* a2d = (const float*)d_in[9];
    const float* b2  = (const float*)d_in[10];
    float* out = (float*)d_out;

    const int Nn = in_sizes[0] / 256;   // 50000
    const int E  = in_sizes[1] / 2;     // 800000
    const int ET = E + Nn;              // with self loops

    size_t off = 0;
    auto carve = [&](size_t bytes) -> void* {
        void* p = (char*)d_ws + off;
        off += (bytes + 255) & ~(size_t)255;
        return p;
    };
    float* h1       = (float*)carve((size_t)Nn * 512 * 4);   // 102.4 MB
    float* h2       = (float*)carve((size_t)Nn * 320 * 4);   // 64 MB
    float* x1       = (float*)carve((size_t)Nn * 64 * 4);    // 12.8 MB
    float* as1      = (float*)carve((size_t)Nn * 8 * 4);
    float* ad1      = (float*)carve((size_t)Nn * 8 * 4);
    float* as2      = (float*)carve((size_t)Nn * 8 * 4);
    float* ad2      = (float*)carve((size_t)Nn * 8 * 4);
    int*   deg      = (int*)carve((size_t)Nn * 4);
    int*   cursor   = (int*)carve((size_t)Nn * 4);
    int*   rowstart = (int*)carve((size_t)(Nn + 1) * 4);
    int*   srcs     = (int*)carve((size_t)ET * 4);

    hipMemsetAsync(deg, 0, (size_t)Nn * 4, stream);
    hipMemsetAsync(cursor, 0, (size_t)Nn * 4, stream);

    // CSR by dst
    hist_k<<<(ET + 255) / 256, 256, 0, stream>>>(ei, deg, E, Nn);
    scan_k<<<1, 1024, 0, stream>>>(deg, rowstart, Nn, ET);
    scatter_k<<<(ET + 255) / 256, 256, 0, stream>>>(ei, rowstart, cursor, srcs, E, Nn);

    // layer 1
    gemm_nt<<<dim3((Nn + 63) / 64, 512 / 64), 256, 0, stream>>>(x, W0, h1, Nn, 512, 256);
    att1_k<<<(Nn + 3) / 4, 256, 0, stream>>>(h1, a0s, a0d, as1, ad1, Nn);
    agg1_k<<<(Nn + 3) / 4, 256, 0, stream>>>(h1, as1, ad1, srcs, rowstart, b0, x1, Nn);

    // layer 2
    gemm_nt<<<dim3((Nn + 63) / 64, 320 / 64), 256, 0, stream>>>(x1, W2, h2, Nn, 320, 64);
    att2_k<<<(Nn * 8 + 255) / 256, 256, 0, stream>>>(h2, a2s, a2d, as2, ad2, Nn);
    agg2_k<<<(Nn + 3) / 4, 256, 0, stream>>>(h2, as2, ad2, srcs, rowstart, b2, out, Nn);
}

// Round 2
// 674.372 us; speedup vs baseline: 1.6098x; 1.6098x over previous
//
#include <hip/hip_runtime.h>
#include <hip/hip_bf16.h>
#include <math.h>

// GATNet round 2: bf16-MFMA GEMM1, bf16 feature storage for gathers,
// lane-contiguous aggregation (16B/lane loads), 2-barrier scan.
// h1b/h2b are bf16 (51/32 MB -> L3-resident); all accumulation fp32.

#define NEG_SLOPE 0.2f

typedef short v8s __attribute__((ext_vector_type(8)));
typedef float v4f __attribute__((ext_vector_type(4)));
typedef unsigned short u16;
typedef unsigned int u32;

__device__ __forceinline__ u16 f2bf(float f) {
    union { float f; u32 u; } v; v.f = f;
    u32 r = v.u + 0x7fffu + ((v.u >> 16) & 1u);
    return (u16)(r >> 16);
}
__device__ __forceinline__ void unp2(u32 u, float& a, float& b) {
    union { u32 u; float f; } x, y;
    x.u = u << 16; y.u = u & 0xffff0000u;
    a = x.f; b = y.f;
}

// ---------------- CSR build ----------------

__global__ __launch_bounds__(256) void hist_k(const int* __restrict__ ei, int* __restrict__ deg,
                                              int E, int Nn) {
    int e = blockIdx.x * 256 + threadIdx.x;
    int ET = E + Nn;
    if (e >= ET) return;
    int d = (e < E) ? ei[E + e] : (e - E);
    atomicAdd(&deg[d], 1);
}

// two-level scan: thread-chunk serial + wave shfl scan + 16-wave scan. 2 barriers.
__global__ __launch_bounds__(1024) void scan_k(const int* __restrict__ deg, int* __restrict__ rowstart,
                                               int n, int total) {
    __shared__ int wsum[16];
    int t = threadIdx.x;
    int chunk = (n + 1023) / 1024;
    int base = t * chunk;
    int s = 0;
    for (int i = 0; i < chunk; i++) {
        int idx = base + i;
        if (idx < n) s += deg[idx];
    }
    int v = s;
    int lane = t & 63;
    for (int off = 1; off < 64; off <<= 1) {
        int u = __shfl_up(v, off, 64);
        if (lane >= off) v += u;
    }
    int wid = t >> 6;
    if (lane == 63) wsum[wid] = v;
    __syncthreads();
    if (t < 16) {
        int w = wsum[t];
        for (int off = 1; off < 16; off <<= 1) {
            int u = __shfl_up(w, off, 64);
            if (t >= off) w += u;
        }
        wsum[t] = w;
    }
    __syncthreads();
    int wpre = (wid > 0) ? wsum[wid - 1] : 0;
    int excl = wpre + v - s;   // exclusive prefix for this thread's chunk
    for (int i = 0; i < chunk; i++) {
        int idx = base + i;
        if (idx < n) { rowstart[idx] = excl; excl += deg[idx]; }
    }
    if (t == 1023) rowstart[n] = total;
}

__global__ __launch_bounds__(256) void scatter_k(const int* __restrict__ ei,
                                                 const int* __restrict__ rowstart,
                                                 int* __restrict__ cursor,
                                                 int* __restrict__ srcs, int E, int Nn) {
    int e = blockIdx.x * 256 + threadIdx.x;
    int ET = E + Nn;
    if (e >= ET) return;
    int s, d;
    if (e < E) { s = ei[e]; d = ei[E + e]; }
    else       { s = e - E; d = e - E; }
    int pos = atomicAdd(&cursor[d], 1);
    srcs[rowstart[d] + pos] = s;
}

// ---------------- fp32 -> bf16 cast ----------------

__global__ __launch_bounds__(256) void cast_k(const float* __restrict__ in, u16* __restrict__ out, int n) {
    int i = (blockIdx.x * 256 + threadIdx.x) * 4;
    if (i + 3 < n) {
        float4 v = *reinterpret_cast<const float4*>(in + i);
        ushort4 o;
        o.x = f2bf(v.x); o.y = f2bf(v.y); o.z = f2bf(v.z); o.w = f2bf(v.w);
        *reinterpret_cast<ushort4*>(out + i) = o;
    } else {
        for (int j = i; j < n; j++) out[j] = f2bf(in[j]);
    }
}

// ---------------- bf16 MFMA GEMM: C[M,512] = A[M,256] * B[512,256]^T ----------------
// 128x128 tile, BK=32, 4 waves each computing a 64x64 quadrant via 4x4 mfma_16x16x32.

__global__ __launch_bounds__(256) void gemm1_mfma(const u16* __restrict__ Ab,
                                                  const u16* __restrict__ Bb,
                                                  u16* __restrict__ Cb, int M) {
    __shared__ u16 As[128][40];   // +8 pad: 2-way-max bank aliasing on ds_read_b128
    __shared__ u16 Bs[128][40];
    const int t = threadIdx.x;
    const int m0 = blockIdx.x * 128;
    const int n0 = blockIdx.y * 128;
    const int w = t >> 6, lane = t & 63;
    const int wr = (w >> 1) * 64, wc = (w & 1) * 64;
    const int q = lane >> 4, l16 = lane & 15;
    const int r0 = t >> 2;          // 0..63
    const int c8 = (t & 3) * 8;     // 0,8,16,24

    v4f acc[4][4];
#pragma unroll
    for (int i = 0; i < 4; i++)
#pragma unroll
        for (int j = 0; j < 4; j++) acc[i][j] = (v4f){0.f, 0.f, 0.f, 0.f};

    for (int kt = 0; kt < 256; kt += 32) {
#pragma unroll
        for (int p = 0; p < 2; p++) {
            int r = r0 + p * 64;
            int gm = m0 + r;
            uint4 va = make_uint4(0u, 0u, 0u, 0u);
            if (gm < M) va = *reinterpret_cast<const uint4*>(Ab + (size_t)gm * 256 + kt + c8);
            *reinterpret_cast<uint4*>(&As[r][c8]) = va;
            uint4 vb = *reinterpret_cast<const uint4*>(Bb + (size_t)(n0 + r) * 256 + kt + c8);
            *reinterpret_cast<uint4*>(&Bs[r][c8]) = vb;
        }
        __syncthreads();
        v8s af[4], bf[4];
#pragma unroll
        for (int i = 0; i < 4; i++) af[i] = *reinterpret_cast<const v8s*>(&As[wr + i * 16 + l16][q * 8]);
#pragma unroll
        for (int j = 0; j < 4; j++) bf[j] = *reinterpret_cast<const v8s*>(&Bs[wc + j * 16 + l16][q * 8]);
#pragma unroll
        for (int i = 0; i < 4; i++)
#pragma unroll
            for (int j = 0; j < 4; j++)
                acc[i][j] = __builtin_amdgcn_mfma_f32_16x16x32_bf16(af[i], bf[j], acc[i][j], 0, 0, 0);
        __syncthreads();
    }
    // C/D: col = lane&15, row = q*4 + reg
#pragma unroll
    for (int i = 0; i < 4; i++) {
#pragma unroll
        for (int r = 0; r < 4; r++) {
            int gm = m0 + wr + i * 16 + q * 4 + r;
            if (gm < M) {
#pragma unroll
                for (int j = 0; j < 4; j++) {
                    int gn = n0 + wc + j * 16 + l16;
                    Cb[(size_t)gm * 512 + gn] = f2bf(acc[i][j][r]);
                }
            }
        }
    }
}

// ---------------- layer-1 attention logits (wave per node, bf16 h1) ----------------

__global__ __launch_bounds__(256) void att1_k(const u16* __restrict__ h1b,
                                              const float* __restrict__ a0s, const float* __restrict__ a0d,
                                              float* __restrict__ as1, float* __restrict__ ad1, int Nn) {
    int wave = threadIdx.x >> 6, lane = threadIdx.x & 63;
    int n = blockIdx.x * 4 + wave;
    if (n >= Nn) return;
    uint4 raw = *reinterpret_cast<const uint4*>(h1b + (size_t)n * 512 + lane * 8);
    float h[8];
    unp2(raw.x, h[0], h[1]); unp2(raw.y, h[2], h[3]);
    unp2(raw.z, h[4], h[5]); unp2(raw.w, h[6], h[7]);
    float s1 = 0.f, s2 = 0.f;
#pragma unroll
    for (int j = 0; j < 8; j++) {
        s1 = fmaf(h[j], a0s[lane * 8 + j], s1);
        s2 = fmaf(h[j], a0d[lane * 8 + j], s2);
    }
#pragma unroll
    for (int off = 1; off < 8; off <<= 1) {
        s1 += __shfl_xor(s1, off, 64);
        s2 += __shfl_xor(s2, off, 64);
    }
    if ((lane & 7) == 0) {
        as1[n * 8 + (lane >> 3)] = s1;
        ad1[n * 8 + (lane >> 3)] = s2;
    }
}

// ---------------- layer-1 aggregation (wave per dst, lane-contiguous bf16 gather) ----------------

__global__ __launch_bounds__(256) void agg1_k(const u16* __restrict__ h1b,
                                              const float* __restrict__ as1, const float* __restrict__ ad1,
                                              const int* __restrict__ srcs, const int* __restrict__ rowstart,
                                              const float* __restrict__ b0, float* __restrict__ x1, int Nn) {
    int wave = threadIdx.x >> 6, lane = threadIdx.x & 63;
    int n = blockIdx.x * 4 + wave;
    if (n >= Nn) return;
    const int hl = lane >> 3;              // head of this lane's 8 channels
    const float adl = ad1[n * 8 + hl];
    float acc[8] = {0, 0, 0, 0, 0, 0, 0, 0};
    float dsum = 0.f;
    int beg = rowstart[n], end = rowstart[n + 1];
    for (int i = beg; i < end; i++) {
        int s = srcs[i];
        uint4 raw = *reinterpret_cast<const uint4*>(h1b + (size_t)s * 512 + lane * 8);
        float e = as1[s * 8 + hl] + adl;
        e = (e > 0.f) ? e : NEG_SLOPE * e;
        float p = __expf(e);
        dsum += p;
        float h[8];
        unp2(raw.x, h[0], h[1]); unp2(raw.y, h[2], h[3]);
        unp2(raw.z, h[4], h[5]); unp2(raw.w, h[6], h[7]);
#pragma unroll
        for (int j = 0; j < 8; j++) acc[j] = fmaf(p, h[j], acc[j]);
    }
    float inv = 1.f / (dsum + 1e-16f);
    float r[8];
#pragma unroll
    for (int j = 0; j < 8; j++) r[j] = acc[j] * inv;
    // sum over heads: reduce over lane bits 3,4,5 (channels (lane&7)*8+j fixed)
#pragma unroll
    for (int j = 0; j < 8; j++) {
        r[j] += __shfl_xor(r[j], 8, 64);
        r[j] += __shfl_xor(r[j], 16, 64);
        r[j] += __shfl_xor(r[j], 32, 64);
    }
    if (lane < 8) {
#pragma unroll
        for (int j = 0; j < 8; j++) {
            float v = r[j] * 0.125f + b0[lane * 8 + j];
            x1[(size_t)n * 64 + lane * 8 + j] = (v > 0.f) ? v : 0.f;
        }
    }
}

// ---------------- fp32 tiled GEMM (layer 2): Cb[M,Nc]=A[M,K]*B[Nc,K]^T, bf16 out ----------------

__global__ __launch_bounds__(256) void gemm_nt(const float* __restrict__ A, const float* __restrict__ B,
                                               u16* __restrict__ Cb, int M, int Nc, int K) {
    __shared__ float As[16][65];
    __shared__ float Bs[16][65];
    const int t  = threadIdx.x;
    const int tx = t & 15, ty = t >> 4;
    const int m0 = blockIdx.x * 64, n0 = blockIdx.y * 64;
    const int lm = t >> 2;
    const int lk = (t & 3) << 2;
    float acc[4][4] = {};
    for (int kt = 0; kt < K; kt += 16) {
        int gm = m0 + lm;
        float4 av;
        if (gm < M) av = *reinterpret_cast<const float4*>(A + (size_t)gm * K + kt + lk);
        else        av = make_float4(0.f, 0.f, 0.f, 0.f);
        As[lk + 0][lm] = av.x; As[lk + 1][lm] = av.y; As[lk + 2][lm] = av.z; As[lk + 3][lm] = av.w;
        float4 bv = *reinterpret_cast<const float4*>(B + (size_t)(n0 + lm) * K + kt + lk);
        Bs[lk + 0][lm] = bv.x; Bs[lk + 1][lm] = bv.y; Bs[lk + 2][lm] = bv.z; Bs[lk + 3][lm] = bv.w;
        __syncthreads();
#pragma unroll
        for (int kk = 0; kk < 16; kk++) {
            float a[4], b[4];
#pragma unroll
            for (int i = 0; i < 4; i++) a[i] = As[kk][ty * 4 + i];
#pragma unroll
            for (int j = 0; j < 4; j++) b[j] = Bs[kk][tx * 4 + j];
#pragma unroll
            for (int i = 0; i < 4; i++)
#pragma unroll
                for (int j = 0; j < 4; j++) acc[i][j] = fmaf(a[i], b[j], acc[i][j]);
        }
        __syncthreads();
    }
#pragma unroll
    for (int i = 0; i < 4; i++) {
        int gm = m0 + ty * 4 + i;
        if (gm < M) {
#pragma unroll
            for (int j = 0; j < 4; j++) Cb[(size_t)gm * Nc + n0 + tx * 4 + j] = f2bf(acc[i][j]);
        }
    }
}

// ---------------- layer-2 attention logits (thread per node*head, bf16 h2) ----------------

__global__ __launch_bounds__(256) void att2_k(const u16* __restrict__ h2b,
                                              const float* __restrict__ a2s, const float* __restrict__ a2d,
                                              float* __restrict__ as2, float* __restrict__ ad2, int Nn) {
    int t = blockIdx.x * 256 + threadIdx.x;
    if (t >= Nn * 8) return;
    int n = t >> 3, h = t & 7;
    const u16* hr = h2b + (size_t)n * 320 + h * 40;
    float s1 = 0.f, s2 = 0.f;
#pragma unroll
    for (int b = 0; b < 5; b++) {
        uint4 raw = *reinterpret_cast<const uint4*>(hr + b * 8);
        float h8[8];
        unp2(raw.x, h8[0], h8[1]); unp2(raw.y, h8[2], h8[3]);
        unp2(raw.z, h8[4], h8[5]); unp2(raw.w, h8[6], h8[7]);
#pragma unroll
        for (int j = 0; j < 8; j++) {
            int c = h * 40 + b * 8 + j;
            s1 = fmaf(h8[j], a2s[c], s1);
            s2 = fmaf(h8[j], a2d[c], s2);
        }
    }
    as2[t] = s1;
    ad2[t] = s2;
}

// ---------------- layer-2 aggregation + head-mean + bias + log_softmax ----------------

__global__ __launch_bounds__(256) void agg2_k(const u16* __restrict__ h2b,
                                              const float* __restrict__ as2, const float* __restrict__ ad2,
                                              const int* __restrict__ srcs, const int* __restrict__ rowstart,
                                              const float* __restrict__ b2, float* __restrict__ out, int Nn) {
    __shared__ float smem[4][320];
    int wave = threadIdx.x >> 6, lane = threadIdx.x & 63;
    int n = blockIdx.x * 4 + wave;
    bool active = (n < Nn);
    bool ld = active && (lane < 40);
    const int hl = lane / 5;               // head of channels 8*lane..8*lane+7 (lane<40)
    float adl = ld ? ad2[n * 8 + hl] : 0.f;
    float acc[8] = {0, 0, 0, 0, 0, 0, 0, 0};
    float dsum = 0.f;
    if (active) {
        int beg = rowstart[n], end = rowstart[n + 1];
        for (int i = beg; i < end; i++) {
            int s = srcs[i];
            if (lane < 40) {
                uint4 raw = *reinterpret_cast<const uint4*>(h2b + (size_t)s * 320 + lane * 8);
                float e = as2[s * 8 + hl] + adl;
                e = (e > 0.f) ? e : NEG_SLOPE * e;
                float p = __expf(e);
                dsum += p;
                float h[8];
                unp2(raw.x, h[0], h[1]); unp2(raw.y, h[2], h[3]);
                unp2(raw.z, h[4], h[5]); unp2(raw.w, h[6], h[7]);
#pragma unroll
                for (int j = 0; j < 8; j++) acc[j] = fmaf(p, h[j], acc[j]);
            }
        }
        if (lane < 40) {
            float inv = 1.f / (dsum + 1e-16f);
#pragma unroll
            for (int j = 0; j < 8; j++) smem[wave][lane * 8 + j] = acc[j] * inv;
        }
    }
    __syncthreads();
    if (active) {
        float v;
        if (lane < 40) {
            float ssum = 0.f;
#pragma unroll
            for (int h = 0; h < 8; h++) ssum += smem[wave][h * 40 + lane];
            v = ssum * 0.125f + b2[lane];
        } else {
            v = -INFINITY;
        }
        float m = v;
        for (int off = 32; off > 0; off >>= 1) m = fmaxf(m, __shfl_xor(m, off, 64));
        float ex = (lane < 40) ? __expf(v - m) : 0.f;
        float se = ex;
        for (int off = 32; off > 0; off >>= 1) se += __shfl_xor(se, off, 64);
        if (lane < 40) out[(size_t)n * 40 + lane] = v - m - __logf(se);
    }
}

// ---------------- launch ----------------

extern "C" void kernel_launch(void* const* d_in, const int* in_sizes, int n_in,
                              void* d_out, int out_size, void* d_ws, size_t ws_size,
                              hipStream_t stream) {
    const float* x   = (const float*)d_in[0];
    const int*   ei  = (const int*)d_in[1];
    const float* W0  = (const float*)d_in[3];
    const float* a0s = (const float*)d_in[4];
    const float* a0d = (const float*)d_in[5];
    const float* b0  = (const float*)d_in[6];
    const float* W2  = (const float*)d_in[7];
    const float* a2s = (const float*)d_in[8];
    const float* a2d = (const float*)d_in[9];
    const float* b2  = (const float*)d_in[10];
    float* out = (float*)d_out;

    const int Nn = in_sizes[0] / 256;   // 50000
    const int E  = in_sizes[1] / 2;     // 800000
    const int ET = E + Nn;

    size_t off = 0;
    auto carve = [&](size_t bytes) -> void* {
        void* p = (char*)d_ws + off;
        off += (bytes + 255) & ~(size_t)255;
        return p;
    };
    u16*   xb       = (u16*)carve((size_t)Nn * 256 * 2);     // 25.6 MB
    u16*   W0b      = (u16*)carve((size_t)512 * 256 * 2);
    u16*   h1b      = (u16*)carve((size_t)Nn * 512 * 2);     // 51.2 MB
    float* x1       = (float*)carve((size_t)Nn * 64 * 4);    // 12.8 MB
    u16*   h2b      = (u16*)carve((size_t)Nn * 320 * 2);     // 32 MB
    float* as1      = (float*)carve((size_t)Nn * 8 * 4);
    float* ad1      = (float*)carve((size_t)Nn * 8 * 4);
    float* as2      = (float*)carve((size_t)Nn * 8 * 4);
    float* ad2      = (float*)carve((size_t)Nn * 8 * 4);
    int*   deg      = (int*)carve((size_t)Nn * 4);
    int*   cursor   = (int*)carve((size_t)Nn * 4);
    int*   rowstart = (int*)carve((size_t)(Nn + 1) * 4);
    int*   srcs     = (int*)carve((size_t)ET * 4);

    hipMemsetAsync(deg, 0, (size_t)Nn * 4, stream);
    hipMemsetAsync(cursor, 0, (size_t)Nn * 4, stream);

    // CSR by dst
    hist_k<<<(ET + 255) / 256, 256, 0, stream>>>(ei, deg, E, Nn);
    scan_k<<<1, 1024, 0, stream>>>(deg, rowstart, Nn, ET);
    scatter_k<<<(ET + 255) / 256, 256, 0, stream>>>(ei, rowstart, cursor, srcs, E, Nn);

    // casts
    cast_k<<<(Nn * 256 / 4 + 255) / 256, 256, 0, stream>>>(x, xb, Nn * 256);
    cast_k<<<(512 * 256 / 4 + 255) / 256, 256, 0, stream>>>(W0, W0b, 512 * 256);

    // layer 1
    gemm1_mfma<<<dim3((Nn + 127) / 128, 4), 256, 0, stream>>>(xb, W0b, h1b, Nn);
    att1_k<<<(Nn + 3) / 4, 256, 0, stream>>>(h1b, a0s, a0d, as1, ad1, Nn);
    agg1_k<<<(Nn + 3) / 4, 256, 0, stream>>>(h1b, as1, ad1, srcs, rowstart, b0, x1, Nn);

    // layer 2
    gemm_nt<<<dim3((Nn + 63) / 64, 320 / 64), 256, 0, stream>>>(x1, W2, h2b, Nn, 320, 64);
    att2_k<<<(Nn * 8 + 255) / 256, 256, 0, stream>>>(h2b, a2s, a2d, as2, ad2, Nn);
    agg2_k<<<(Nn + 3) / 4, 256, 0, stream>>>(h2b, as2, ad2, srcs, rowstart, b2, out, Nn);
}

// Round 3
// 574.397 us; speedup vs baseline: 1.8900x; 1.1741x over previous
//
#include <hip/hip_runtime.h>
#include <hip/hip_bf16.h>
#include <math.h>

// GATNet round 3: 4x-unrolled latency-hiding aggregation gathers,
// bf16 MFMA for BOTH layer GEMMs (generic tile), bf16 x1.
// agg FETCH is at the compulsory 8-XCD L2-fill floor; attack latency not bytes.

#define NEG_SLOPE 0.2f

typedef short v8s __attribute__((ext_vector_type(8)));
typedef float v4f __attribute__((ext_vector_type(4)));
typedef unsigned short u16;
typedef unsigned int u32;

__device__ __forceinline__ u16 f2bf(float f) {
    union { float f; u32 u; } v; v.f = f;
    u32 r = v.u + 0x7fffu + ((v.u >> 16) & 1u);
    return (u16)(r >> 16);
}
__device__ __forceinline__ void unp2(u32 u, float& a, float& b) {
    union { u32 u; float f; } x, y;
    x.u = u << 16; y.u = u & 0xffff0000u;
    a = x.f; b = y.f;
}
__device__ __forceinline__ void unp8(uint4 raw, float* h) {
    unp2(raw.x, h[0], h[1]); unp2(raw.y, h[2], h[3]);
    unp2(raw.z, h[4], h[5]); unp2(raw.w, h[6], h[7]);
}
__device__ __forceinline__ float lrelu_exp(float e) {
    e = (e > 0.f) ? e : NEG_SLOPE * e;
    return __expf(e);
}

// ---------------- CSR build ----------------

__global__ __launch_bounds__(256) void hist_k(const int* __restrict__ ei, int* __restrict__ deg,
                                              int E, int Nn) {
    int e = blockIdx.x * 256 + threadIdx.x;
    int ET = E + Nn;
    if (e >= ET) return;
    int d = (e < E) ? ei[E + e] : (e - E);
    atomicAdd(&deg[d], 1);
}

__global__ __launch_bounds__(1024) void scan_k(const int* __restrict__ deg, int* __restrict__ rowstart,
                                               int n, int total) {
    __shared__ int wsum[16];
    int t = threadIdx.x;
    int chunk = (n + 1023) / 1024;
    int base = t * chunk;
    int s = 0;
    for (int i = 0; i < chunk; i++) {
        int idx = base + i;
        if (idx < n) s += deg[idx];
    }
    int v = s;
    int lane = t & 63;
    for (int off = 1; off < 64; off <<= 1) {
        int u = __shfl_up(v, off, 64);
        if (lane >= off) v += u;
    }
    int wid = t >> 6;
    if (lane == 63) wsum[wid] = v;
    __syncthreads();
    if (t < 16) {
        int w = wsum[t];
        for (int off = 1; off < 16; off <<= 1) {
            int u = __shfl_up(w, off, 64);
            if (t >= off) w += u;
        }
        wsum[t] = w;
    }
    __syncthreads();
    int wpre = (wid > 0) ? wsum[wid - 1] : 0;
    int excl = wpre + v - s;
    for (int i = 0; i < chunk; i++) {
        int idx = base + i;
        if (idx < n) { rowstart[idx] = excl; excl += deg[idx]; }
    }
    if (t == 1023) rowstart[n] = total;
}

__global__ __launch_bounds__(256) void scatter_k(const int* __restrict__ ei,
                                                 const int* __restrict__ rowstart,
                                                 int* __restrict__ cursor,
                                                 int* __restrict__ srcs, int E, int Nn) {
    int e = blockIdx.x * 256 + threadIdx.x;
    int ET = E + Nn;
    if (e >= ET) return;
    int s, d;
    if (e < E) { s = ei[e]; d = ei[E + e]; }
    else       { s = e - E; d = e - E; }
    int pos = atomicAdd(&cursor[d], 1);
    srcs[rowstart[d] + pos] = s;
}

// ---------------- fp32 -> bf16 cast ----------------

__global__ __launch_bounds__(256) void cast_k(const float* __restrict__ in, u16* __restrict__ out, int n) {
    int i = (blockIdx.x * 256 + threadIdx.x) * 4;
    if (i + 3 < n) {
        float4 v = *reinterpret_cast<const float4*>(in + i);
        ushort4 o;
        o.x = f2bf(v.x); o.y = f2bf(v.y); o.z = f2bf(v.z); o.w = f2bf(v.w);
        *reinterpret_cast<ushort4*>(out + i) = o;
    } else {
        for (int j = i; j < n; j++) out[j] = f2bf(in[j]);
    }
}

// ---------------- bf16 MFMA GEMM: C[M,Nc] = A[M,K] * B[Nc,K]^T ----------------
// 128x128 tile, BK=32, 4 waves, 4x4 mfma_16x16x32 each. Nc-guarded B/C.

__global__ __launch_bounds__(256) void gemm_mfma(const u16* __restrict__ Ab,
                                                 const u16* __restrict__ Bb,
                                                 u16* __restrict__ Cb, int M, int Nc, int K) {
    __shared__ u16 As[128][40];
    __shared__ u16 Bs[128][40];
    const int t = threadIdx.x;
    const int m0 = blockIdx.x * 128;
    const int n0 = blockIdx.y * 128;
    const int w = t >> 6, lane = t & 63;
    const int wr = (w >> 1) * 64, wc = (w & 1) * 64;
    const int q = lane >> 4, l16 = lane & 15;
    const int r0 = t >> 2;
    const int c8 = (t & 3) * 8;

    v4f acc[4][4];
#pragma unroll
    for (int i = 0; i < 4; i++)
#pragma unroll
        for (int j = 0; j < 4; j++) acc[i][j] = (v4f){0.f, 0.f, 0.f, 0.f};

    for (int kt = 0; kt < K; kt += 32) {
#pragma unroll
        for (int p = 0; p < 2; p++) {
            int r = r0 + p * 64;
            int gm = m0 + r;
            uint4 va = make_uint4(0u, 0u, 0u, 0u);
            if (gm < M) va = *reinterpret_cast<const uint4*>(Ab + (size_t)gm * K + kt + c8);
            *reinterpret_cast<uint4*>(&As[r][c8]) = va;
            int gn = n0 + r;
            uint4 vb = make_uint4(0u, 0u, 0u, 0u);
            if (gn < Nc) vb = *reinterpret_cast<const uint4*>(Bb + (size_t)gn * K + kt + c8);
            *reinterpret_cast<uint4*>(&Bs[r][c8]) = vb;
        }
        __syncthreads();
        v8s af[4], bf[4];
#pragma unroll
        for (int i = 0; i < 4; i++) af[i] = *reinterpret_cast<const v8s*>(&As[wr + i * 16 + l16][q * 8]);
#pragma unroll
        for (int j = 0; j < 4; j++) bf[j] = *reinterpret_cast<const v8s*>(&Bs[wc + j * 16 + l16][q * 8]);
#pragma unroll
        for (int i = 0; i < 4; i++)
#pragma unroll
            for (int j = 0; j < 4; j++)
                acc[i][j] = __builtin_amdgcn_mfma_f32_16x16x32_bf16(af[i], bf[j], acc[i][j], 0, 0, 0);
        __syncthreads();
    }
#pragma unroll
    for (int i = 0; i < 4; i++) {
#pragma unroll
        for (int r = 0; r < 4; r++) {
            int gm = m0 + wr + i * 16 + q * 4 + r;
            if (gm < M) {
#pragma unroll
                for (int j = 0; j < 4; j++) {
                    int gn = n0 + wc + j * 16 + l16;
                    if (gn < Nc) Cb[(size_t)gm * Nc + gn] = f2bf(acc[i][j][r]);
                }
            }
        }
    }
}

// ---------------- layer-1 attention logits (wave per node, bf16 h1) ----------------

__global__ __launch_bounds__(256) void att1_k(const u16* __restrict__ h1b,
                                              const float* __restrict__ a0s, const float* __restrict__ a0d,
                                              float* __restrict__ as1, float* __restrict__ ad1, int Nn) {
    int wave = threadIdx.x >> 6, lane = threadIdx.x & 63;
    int n = blockIdx.x * 4 + wave;
    if (n >= Nn) return;
    uint4 raw = *reinterpret_cast<const uint4*>(h1b + (size_t)n * 512 + lane * 8);
    float h[8];
    unp8(raw, h);
    float s1 = 0.f, s2 = 0.f;
#pragma unroll
    for (int j = 0; j < 8; j++) {
        s1 = fmaf(h[j], a0s[lane * 8 + j], s1);
        s2 = fmaf(h[j], a0d[lane * 8 + j], s2);
    }
#pragma unroll
    for (int off = 1; off < 8; off <<= 1) {
        s1 += __shfl_xor(s1, off, 64);
        s2 += __shfl_xor(s2, off, 64);
    }
    if ((lane & 7) == 0) {
        as1[n * 8 + (lane >> 3)] = s1;
        ad1[n * 8 + (lane >> 3)] = s2;
    }
}

// ---------------- layer-1 aggregation: wave/dst, 4x-unrolled gather, bf16 x1 out ----------------

__global__ __launch_bounds__(256) void agg1_k(const u16* __restrict__ h1b,
                                              const float* __restrict__ as1, const float* __restrict__ ad1,
                                              const int* __restrict__ srcs, const int* __restrict__ rowstart,
                                              const float* __restrict__ b0, u16* __restrict__ x1b, int Nn) {
    int wave = threadIdx.x >> 6, lane = threadIdx.x & 63;
    int n = blockIdx.x * 4 + wave;
    if (n >= Nn) return;
    const int hl = lane >> 3;
    const float adl = ad1[n * 8 + hl];
    float acc[8] = {0, 0, 0, 0, 0, 0, 0, 0};
    float dsum = 0.f;
    int beg = rowstart[n], end = rowstart[n + 1];
    int i = beg;
    for (; i + 4 <= end; i += 4) {
        int s0 = srcs[i + 0], s1 = srcs[i + 1], s2 = srcs[i + 2], s3 = srcs[i + 3];
        uint4 r0 = *reinterpret_cast<const uint4*>(h1b + (size_t)s0 * 512 + lane * 8);
        uint4 r1 = *reinterpret_cast<const uint4*>(h1b + (size_t)s1 * 512 + lane * 8);
        uint4 r2 = *reinterpret_cast<const uint4*>(h1b + (size_t)s2 * 512 + lane * 8);
        uint4 r3 = *reinterpret_cast<const uint4*>(h1b + (size_t)s3 * 512 + lane * 8);
        float e0 = as1[s0 * 8 + hl], e1 = as1[s1 * 8 + hl];
        float e2 = as1[s2 * 8 + hl], e3 = as1[s3 * 8 + hl];
        float p0 = lrelu_exp(e0 + adl), p1 = lrelu_exp(e1 + adl);
        float p2 = lrelu_exp(e2 + adl), p3 = lrelu_exp(e3 + adl);
        dsum += (p0 + p1) + (p2 + p3);
        float h0[8], h1v[8], h2v[8], h3[8];
        unp8(r0, h0); unp8(r1, h1v); unp8(r2, h2v); unp8(r3, h3);
#pragma unroll
        for (int j = 0; j < 8; j++) {
            acc[j] = fmaf(p0, h0[j], acc[j]);
            acc[j] = fmaf(p1, h1v[j], acc[j]);
            acc[j] = fmaf(p2, h2v[j], acc[j]);
            acc[j] = fmaf(p3, h3[j], acc[j]);
        }
    }
    for (; i < end; i++) {
        int s = srcs[i];
        uint4 raw = *reinterpret_cast<const uint4*>(h1b + (size_t)s * 512 + lane * 8);
        float p = lrelu_exp(as1[s * 8 + hl] + adl);
        dsum += p;
        float h[8];
        unp8(raw, h);
#pragma unroll
        for (int j = 0; j < 8; j++) acc[j] = fmaf(p, h[j], acc[j]);
    }
    float inv = 1.f / (dsum + 1e-16f);
    float r[8];
#pragma unroll
    for (int j = 0; j < 8; j++) r[j] = acc[j] * inv;
#pragma unroll
    for (int j = 0; j < 8; j++) {
        r[j] += __shfl_xor(r[j], 8, 64);
        r[j] += __shfl_xor(r[j], 16, 64);
        r[j] += __shfl_xor(r[j], 32, 64);
    }
    if (lane < 8) {
        u16 o[8];
#pragma unroll
        for (int j = 0; j < 8; j++) {
            float v = r[j] * 0.125f + b0[lane * 8 + j];
            o[j] = f2bf((v > 0.f) ? v : 0.f);
        }
        *reinterpret_cast<uint4*>(x1b + (size_t)n * 64 + lane * 8) =
            *reinterpret_cast<const uint4*>(o);
    }
}

// ---------------- layer-2 attention logits ----------------

__global__ __launch_bounds__(256) void att2_k(const u16* __restrict__ h2b,
                                              const float* __restrict__ a2s, const float* __restrict__ a2d,
                                              float* __restrict__ as2, float* __restrict__ ad2, int Nn) {
    int t = blockIdx.x * 256 + threadIdx.x;
    if (t >= Nn * 8) return;
    int n = t >> 3, h = t & 7;
    const u16* hr = h2b + (size_t)n * 320 + h * 40;
    float s1 = 0.f, s2 = 0.f;
#pragma unroll
    for (int b = 0; b < 5; b++) {
        uint4 raw = *reinterpret_cast<const uint4*>(hr + b * 8);
        float h8[8];
        unp8(raw, h8);
#pragma unroll
        for (int j = 0; j < 8; j++) {
            int c = h * 40 + b * 8 + j;
            s1 = fmaf(h8[j], a2s[c], s1);
            s2 = fmaf(h8[j], a2d[c], s2);
        }
    }
    as2[t] = s1;
    ad2[t] = s2;
}

// ---------------- layer-2 aggregation + head-mean + bias + log_softmax ----------------

__global__ __launch_bounds__(256) void agg2_k(const u16* __restrict__ h2b,
                                              const float* __restrict__ as2, const float* __restrict__ ad2,
                                              const int* __restrict__ srcs, const int* __restrict__ rowstart,
                                              const float* __restrict__ b2, float* __restrict__ out, int Nn) {
    __shared__ float smem[4][320];
    int wave = threadIdx.x >> 6, lane = threadIdx.x & 63;
    int n = blockIdx.x * 4 + wave;
    bool active = (n < Nn);
    bool ld = active && (lane < 40);
    const int hl = lane / 5;
    float adl = ld ? ad2[n * 8 + hl] : 0.f;
    float acc[8] = {0, 0, 0, 0, 0, 0, 0, 0};
    float dsum = 0.f;
    if (ld) {
        const size_t loff = (size_t)lane * 8;
        int beg = rowstart[n], end = rowstart[n + 1];
        int i = beg;
        for (; i + 4 <= end; i += 4) {
            int s0 = srcs[i + 0], s1 = srcs[i + 1], s2 = srcs[i + 2], s3 = srcs[i + 3];
            uint4 r0 = *reinterpret_cast<const uint4*>(h2b + (size_t)s0 * 320 + loff);
            uint4 r1 = *reinterpret_cast<const uint4*>(h2b + (size_t)s1 * 320 + loff);
            uint4 r2 = *reinterpret_cast<const uint4*>(h2b + (size_t)s2 * 320 + loff);
            uint4 r3 = *reinterpret_cast<const uint4*>(h2b + (size_t)s3 * 320 + loff);
            float e0 = as2[s0 * 8 + hl], e1 = as2[s1 * 8 + hl];
            float e2 = as2[s2 * 8 + hl], e3 = as2[s3 * 8 + hl];
            float p0 = lrelu_exp(e0 + adl), p1 = lrelu_exp(e1 + adl);
            float p2 = lrelu_exp(e2 + adl), p3 = lrelu_exp(e3 + adl);
            dsum += (p0 + p1) + (p2 + p3);
            float h0[8], h1v[8], h2v[8], h3[8];
            unp8(r0, h0); unp8(r1, h1v); unp8(r2, h2v); unp8(r3, h3);
#pragma unroll
            for (int j = 0; j < 8; j++) {
                acc[j] = fmaf(p0, h0[j], acc[j]);
                acc[j] = fmaf(p1, h1v[j], acc[j]);
                acc[j] = fmaf(p2, h2v[j], acc[j]);
                acc[j] = fmaf(p3, h3[j], acc[j]);
            }
        }
        for (; i < end; i++) {
            int s = srcs[i];
            uint4 raw = *reinterpret_cast<const uint4*>(h2b + (size_t)s * 320 + loff);
            float p = lrelu_exp(as2[s * 8 + hl] + adl);
            dsum += p;
            float h[8];
            unp8(raw, h);
#pragma unroll
            for (int j = 0; j < 8; j++) acc[j] = fmaf(p, h[j], acc[j]);
        }
        float inv = 1.f / (dsum + 1e-16f);
#pragma unroll
        for (int j = 0; j < 8; j++) smem[wave][lane * 8 + j] = acc[j] * inv;
    }
    __syncthreads();
    if (active) {
        float v;
        if (lane < 40) {
            float ssum = 0.f;
#pragma unroll
            for (int h = 0; h < 8; h++) ssum += smem[wave][h * 40 + lane];
            v = ssum * 0.125f + b2[lane];
        } else {
            v = -INFINITY;
        }
        float m = v;
        for (int off = 32; off > 0; off >>= 1) m = fmaxf(m, __shfl_xor(m, off, 64));
        float ex = (lane < 40) ? __expf(v - m) : 0.f;
        float se = ex;
        for (int off = 32; off > 0; off >>= 1) se += __shfl_xor(se, off, 64);
        if (lane < 40) out[(size_t)n * 40 + lane] = v - m - __logf(se);
    }
}

// ---------------- launch ----------------

extern "C" void kernel_launch(void* const* d_in, const int* in_sizes, int n_in,
                              void* d_out, int out_size, void* d_ws, size_t ws_size,
                              hipStream_t stream) {
    const float* x   = (const float*)d_in[0];
    const int*   ei  = (const int*)d_in[1];
    const float* W0  = (const float*)d_in[3];
    const float* a0s = (const float*)d_in[4];
    const float* a0d = (const float*)d_in[5];
    const float* b0  = (const float*)d_in[6];
    const float* W2  = (const float*)d_in[7];
    const float* a2s = (const float*)d_in[8];
    const float* a2d = (const float*)d_in[9];
    const float* b2  = (const float*)d_in[10];
    float* out = (float*)d_out;

    const int Nn = in_sizes[0] / 256;   // 50000
    const int E  = in_sizes[1] / 2;     // 800000
    const int ET = E + Nn;

    size_t off = 0;
    auto carve = [&](size_t bytes) -> void* {
        void* p = (char*)d_ws + off;
        off += (bytes + 255) & ~(size_t)255;
        return p;
    };
    u16*   xb       = (u16*)carve((size_t)Nn * 256 * 2);
    u16*   W0b      = (u16*)carve((size_t)512 * 256 * 2);
    u16*   W2b      = (u16*)carve((size_t)320 * 64 * 2);
    u16*   h1b      = (u16*)carve((size_t)Nn * 512 * 2);
    u16*   x1b      = (u16*)carve((size_t)Nn * 64 * 2);
    u16*   h2b      = (u16*)carve((size_t)Nn * 320 * 2);
    float* as1      = (float*)carve((size_t)Nn * 8 * 4);
    float* ad1      = (float*)carve((size_t)Nn * 8 * 4);
    float* as2      = (float*)carve((size_t)Nn * 8 * 4);
    float* ad2      = (float*)carve((size_t)Nn * 8 * 4);
    int*   deg      = (int*)carve((size_t)Nn * 4);
    int*   cursor   = (int*)carve((size_t)Nn * 4);
    int*   rowstart = (int*)carve((size_t)(Nn + 1) * 4);
    int*   srcs     = (int*)carve((size_t)ET * 4);

    hipMemsetAsync(deg, 0, (size_t)Nn * 4, stream);
    hipMemsetAsync(cursor, 0, (size_t)Nn * 4, stream);

    hist_k<<<(ET + 255) / 256, 256, 0, stream>>>(ei, deg, E, Nn);
    scan_k<<<1, 1024, 0, stream>>>(deg, rowstart, Nn, ET);
    scatter_k<<<(ET + 255) / 256, 256, 0, stream>>>(ei, rowstart, cursor, srcs, E, Nn);

    cast_k<<<(Nn * 256 / 4 + 255) / 256, 256, 0, stream>>>(x, xb, Nn * 256);
    cast_k<<<(512 * 256 / 4 + 255) / 256, 256, 0, stream>>>(W0, W0b, 512 * 256);
    cast_k<<<(320 * 64 / 4 + 255) / 256, 256, 0, stream>>>(W2, W2b, 320 * 64);

    // layer 1
    gemm_mfma<<<dim3((Nn + 127) / 128, 4), 256, 0, stream>>>(xb, W0b, h1b, Nn, 512, 256);
    att1_k<<<(Nn + 3) / 4, 256, 0, stream>>>(h1b, a0s, a0d, as1, ad1, Nn);
    agg1_k<<<(Nn + 3) / 4, 256, 0, stream>>>(h1b, as1, ad1, srcs, rowstart, b0, x1b, Nn);

    // layer 2
    gemm_mfma<<<dim3((Nn + 127) / 128, 3), 256, 0, stream>>>(x1b, W2b, h2b, Nn, 320, 64);
    att2_k<<<(Nn * 8 + 255) / 256, 256, 0, stream>>>(h2b, a2s, a2d, as2, ad2, Nn);
    agg2_k<<<(Nn + 3) / 4, 256, 0, stream>>>(h2b, as2, ad2, srcs, rowstart, b2, out, Nn);
}

// Round 4
// 524.949 us; speedup vs baseline: 2.0680x; 1.0942x over previous
//
#include <hip/hip_runtime.h>
#include <hip/hip_bf16.h>
#include <math.h>

// GATNet round 4: fp8-e4m3 message tables (halves the compulsory 8-XCD
// L2-fill floor of the random gathers), att1 fused into gemm1 epilogue
// (fp32-accurate logits via 16-lane reduce + atomicAdd), 8-deep pipelined
// aggregation gathers. Logits layer2 from fp8 h2 (40-ch dots, small error).

#define NEG_SLOPE 0.2f

typedef short v8s __attribute__((ext_vector_type(8)));
typedef float v4f __attribute__((ext_vector_type(4)));
typedef float v2f __attribute__((ext_vector_type(2)));
typedef unsigned short u16;
typedef unsigned int u32;
typedef unsigned char u8;

__device__ __forceinline__ u16 f2bf(float f) {
    union { float f; u32 u; } v; v.f = f;
    u32 r = v.u + 0x7fffu + ((v.u >> 16) & 1u);
    return (u16)(r >> 16);
}
__device__ __forceinline__ void unp2(u32 u, float& a, float& b) {
    union { u32 u; float f; } x, y;
    x.u = u << 16; y.u = u & 0xffff0000u;
    a = x.f; b = y.f;
}
__device__ __forceinline__ float lrelu_exp(float e) {
    e = (e > 0.f) ? e : NEG_SLOPE * e;
    return __expf(e);
}
// decode 8 fp8-e4m3 bytes -> 8 floats
__device__ __forceinline__ void dec8(uint2 r, float* h) {
    v2f a = __builtin_amdgcn_cvt_pk_f32_fp8(r.x, false);
    v2f b = __builtin_amdgcn_cvt_pk_f32_fp8(r.x, true);
    v2f c = __builtin_amdgcn_cvt_pk_f32_fp8(r.y, false);
    v2f d = __builtin_amdgcn_cvt_pk_f32_fp8(r.y, true);
    h[0] = a.x; h[1] = a.y; h[2] = b.x; h[3] = b.y;
    h[4] = c.x; h[5] = c.y; h[6] = d.x; h[7] = d.y;
}
__device__ __forceinline__ u8 enc8(float v) {
    u32 p = __builtin_amdgcn_cvt_pk_fp8_f32(v, v, 0u, false);
    return (u8)(p & 0xffu);
}

// ---------------- CSR build ----------------

__global__ __launch_bounds__(256) void hist_k(const int* __restrict__ ei, int* __restrict__ deg,
                                              int E, int Nn) {
    int e = blockIdx.x * 256 + threadIdx.x;
    int ET = E + Nn;
    if (e >= ET) return;
    int d = (e < E) ? ei[E + e] : (e - E);
    atomicAdd(&deg[d], 1);
}

__global__ __launch_bounds__(1024) void scan_k(const int* __restrict__ deg, int* __restrict__ rowstart,
                                               int n, int total) {
    __shared__ int wsum[16];
    int t = threadIdx.x;
    int chunk = (n + 1023) / 1024;
    int base = t * chunk;
    int s = 0;
    for (int i = 0; i < chunk; i++) {
        int idx = base + i;
        if (idx < n) s += deg[idx];
    }
    int v = s;
    int lane = t & 63;
    for (int off = 1; off < 64; off <<= 1) {
        int u = __shfl_up(v, off, 64);
        if (lane >= off) v += u;
    }
    int wid = t >> 6;
    if (lane == 63) wsum[wid] = v;
    __syncthreads();
    if (t < 16) {
        int w = wsum[t];
        for (int off = 1; off < 16; off <<= 1) {
            int u = __shfl_up(w, off, 64);
            if (t >= off) w += u;
        }
        wsum[t] = w;
    }
    __syncthreads();
    int wpre = (wid > 0) ? wsum[wid - 1] : 0;
    int excl = wpre + v - s;
    for (int i = 0; i < chunk; i++) {
        int idx = base + i;
        if (idx < n) { rowstart[idx] = excl; excl += deg[idx]; }
    }
    if (t == 1023) rowstart[n] = total;
}

__global__ __launch_bounds__(256) void scatter_k(const int* __restrict__ ei,
                                                 const int* __restrict__ rowstart,
                                                 int* __restrict__ cursor,
                                                 int* __restrict__ srcs, int E, int Nn) {
    int e = blockIdx.x * 256 + threadIdx.x;
    int ET = E + Nn;
    if (e >= ET) return;
    int s, d;
    if (e < E) { s = ei[e]; d = ei[E + e]; }
    else       { s = e - E; d = e - E; }
    int pos = atomicAdd(&cursor[d], 1);
    srcs[rowstart[d] + pos] = s;
}

// ---------------- fp32 -> bf16 cast ----------------

__global__ __launch_bounds__(256) void cast_k(const float* __restrict__ in, u16* __restrict__ out, int n) {
    int i = (blockIdx.x * 256 + threadIdx.x) * 4;
    if (i + 3 < n) {
        float4 v = *reinterpret_cast<const float4*>(in + i);
        ushort4 o;
        o.x = f2bf(v.x); o.y = f2bf(v.y); o.z = f2bf(v.z); o.w = f2bf(v.w);
        *reinterpret_cast<ushort4*>(out + i) = o;
    } else {
        for (int j = i; j < n; j++) out[j] = f2bf(in[j]);
    }
}

// ---------------- bf16 MFMA GEMM -> fp8 C, optional fused attention logits ----------------
// C[M,Nc] = A[M,K]*B[Nc,K]^T stored as fp8-e4m3. If as_out!=null, also
// as_out[m,h] += sum_c C[m,c]*avs_vec[c] (fp32 acc, head = col>>6; requires
// 64-aligned heads, true for layer 1).

__global__ __launch_bounds__(256) void gemm_mfma(const u16* __restrict__ Ab,
                                                 const u16* __restrict__ Bb,
                                                 u8* __restrict__ Cf, int M, int Nc, int K,
                                                 const float* __restrict__ avs_vec,
                                                 const float* __restrict__ avd_vec,
                                                 float* as_out, float* ad_out) {
    __shared__ u16 As[128][40];
    __shared__ u16 Bs[128][40];
    const int t = threadIdx.x;
    const int m0 = blockIdx.x * 128;
    const int n0 = blockIdx.y * 128;
    const int w = t >> 6, lane = t & 63;
    const int wr = (w >> 1) * 64, wc = (w & 1) * 64;
    const int q = lane >> 4, l16 = lane & 15;
    const int r0 = t >> 2;
    const int c8 = (t & 3) * 8;

    v4f acc[4][4];
#pragma unroll
    for (int i = 0; i < 4; i++)
#pragma unroll
        for (int j = 0; j < 4; j++) acc[i][j] = (v4f){0.f, 0.f, 0.f, 0.f};

    for (int kt = 0; kt < K; kt += 32) {
#pragma unroll
        for (int p = 0; p < 2; p++) {
            int r = r0 + p * 64;
            int gm = m0 + r;
            uint4 va = make_uint4(0u, 0u, 0u, 0u);
            if (gm < M) va = *reinterpret_cast<const uint4*>(Ab + (size_t)gm * K + kt + c8);
            *reinterpret_cast<uint4*>(&As[r][c8]) = va;
            int gn = n0 + r;
            uint4 vb = make_uint4(0u, 0u, 0u, 0u);
            if (gn < Nc) vb = *reinterpret_cast<const uint4*>(Bb + (size_t)gn * K + kt + c8);
            *reinterpret_cast<uint4*>(&Bs[r][c8]) = vb;
        }
        __syncthreads();
        v8s af[4], bf[4];
#pragma unroll
        for (int i = 0; i < 4; i++) af[i] = *reinterpret_cast<const v8s*>(&As[wr + i * 16 + l16][q * 8]);
#pragma unroll
        for (int j = 0; j < 4; j++) bf[j] = *reinterpret_cast<const v8s*>(&Bs[wc + j * 16 + l16][q * 8]);
#pragma unroll
        for (int i = 0; i < 4; i++)
#pragma unroll
            for (int j = 0; j < 4; j++)
                acc[i][j] = __builtin_amdgcn_mfma_f32_16x16x32_bf16(af[i], bf[j], acc[i][j], 0, 0, 0);
        __syncthreads();
    }

    const bool do_att = (as_out != nullptr);
    float avs[4], avd[4];
    if (do_att) {
#pragma unroll
        for (int j = 0; j < 4; j++) {
            int gn = n0 + wc + j * 16 + l16;
            avs[j] = (gn < Nc) ? avs_vec[gn] : 0.f;
            avd[j] = (gn < Nc) ? avd_vec[gn] : 0.f;
        }
    }
    const int head = (n0 + wc) >> 6;   // layer-1: heads 64-aligned within slab

#pragma unroll
    for (int i = 0; i < 4; i++) {
#pragma unroll
        for (int r = 0; r < 4; r++) {
            int gm = m0 + wr + i * 16 + q * 4 + r;
            if (gm < M) {
#pragma unroll
                for (int j = 0; j < 4; j++) {
                    int gn = n0 + wc + j * 16 + l16;
                    if (gn < Nc) Cf[(size_t)gm * Nc + gn] = enc8(acc[i][j][r]);
                }
            }
            if (do_att) {
                float ps = 0.f, pd = 0.f;
#pragma unroll
                for (int j = 0; j < 4; j++) {
                    float v = acc[i][j][r];
                    ps = fmaf(v, avs[j], ps);
                    pd = fmaf(v, avd[j], pd);
                }
#pragma unroll
                for (int m = 1; m < 16; m <<= 1) {
                    ps += __shfl_xor(ps, m, 64);
                    pd += __shfl_xor(pd, m, 64);
                }
                if (l16 == 0 && gm < M) {
                    atomicAdd(&as_out[gm * 8 + head], ps);
                    atomicAdd(&ad_out[gm * 8 + head], pd);
                }
            }
        }
    }
}

// ---------------- layer-1 aggregation: wave/dst, 8-deep fp8 gather, bf16 x1 out ----------------

__global__ __launch_bounds__(256) void agg1_k(const u8* __restrict__ h1f,
                                              const float* __restrict__ as1, const float* __restrict__ ad1,
                                              const int* __restrict__ srcs, const int* __restrict__ rowstart,
                                              const float* __restrict__ b0, u16* __restrict__ x1b, int Nn) {
    int wave = threadIdx.x >> 6, lane = threadIdx.x & 63;
    int n = blockIdx.x * 4 + wave;
    if (n >= Nn) return;
    const int hl = lane >> 3;
    const float adl = ad1[n * 8 + hl];
    const size_t loff = (size_t)lane * 8;
    float acc[8] = {0, 0, 0, 0, 0, 0, 0, 0};
    float dsum = 0.f;
    int beg = rowstart[n], end = rowstart[n + 1];
    int i = beg;
    for (; i + 8 <= end; i += 8) {
        int s[8];
#pragma unroll
        for (int u = 0; u < 8; u++) s[u] = srcs[i + u];
        uint2 rw[8];
#pragma unroll
        for (int u = 0; u < 8; u++) rw[u] = *reinterpret_cast<const uint2*>(h1f + (size_t)s[u] * 512 + loff);
        float eg[8];
#pragma unroll
        for (int u = 0; u < 8; u++) eg[u] = as1[s[u] * 8 + hl];
        float p[8];
#pragma unroll
        for (int u = 0; u < 8; u++) { p[u] = lrelu_exp(eg[u] + adl); dsum += p[u]; }
#pragma unroll
        for (int u = 0; u < 8; u++) {
            float hv[8];
            dec8(rw[u], hv);
#pragma unroll
            for (int j = 0; j < 8; j++) acc[j] = fmaf(p[u], hv[j], acc[j]);
        }
    }
    for (; i + 4 <= end; i += 4) {
        int s[4];
#pragma unroll
        for (int u = 0; u < 4; u++) s[u] = srcs[i + u];
        uint2 rw[4];
#pragma unroll
        for (int u = 0; u < 4; u++) rw[u] = *reinterpret_cast<const uint2*>(h1f + (size_t)s[u] * 512 + loff);
#pragma unroll
        for (int u = 0; u < 4; u++) {
            float p = lrelu_exp(as1[s[u] * 8 + hl] + adl);
            dsum += p;
            float hv[8];
            dec8(rw[u], hv);
#pragma unroll
            for (int j = 0; j < 8; j++) acc[j] = fmaf(p, hv[j], acc[j]);
        }
    }
    for (; i < end; i++) {
        int s = srcs[i];
        uint2 raw = *reinterpret_cast<const uint2*>(h1f + (size_t)s * 512 + loff);
        float p = lrelu_exp(as1[s * 8 + hl] + adl);
        dsum += p;
        float hv[8];
        dec8(raw, hv);
#pragma unroll
        for (int j = 0; j < 8; j++) acc[j] = fmaf(p, hv[j], acc[j]);
    }
    float inv = 1.f / (dsum + 1e-16f);
    float r[8];
#pragma unroll
    for (int j = 0; j < 8; j++) r[j] = acc[j] * inv;
#pragma unroll
    for (int j = 0; j < 8; j++) {
        r[j] += __shfl_xor(r[j], 8, 64);
        r[j] += __shfl_xor(r[j], 16, 64);
        r[j] += __shfl_xor(r[j], 32, 64);
    }
    if (lane < 8) {
        u16 o[8];
#pragma unroll
        for (int j = 0; j < 8; j++) {
            float v = r[j] * 0.125f + b0[lane * 8 + j];
            o[j] = f2bf((v > 0.f) ? v : 0.f);
        }
        *reinterpret_cast<uint4*>(x1b + (size_t)n * 64 + lane * 8) =
            *reinterpret_cast<const uint4*>(o);
    }
}

// ---------------- layer-2 attention logits (thread per node*head, fp8 h2) ----------------

__global__ __launch_bounds__(256) void att2_k(const u8* __restrict__ h2f,
                                              const float* __restrict__ a2s, const float* __restrict__ a2d,
                                              float* __restrict__ as2, float* __restrict__ ad2, int Nn) {
    int t = blockIdx.x * 256 + threadIdx.x;
    if (t >= Nn * 8) return;
    int n = t >> 3, h = t & 7;
    const u8* hr = h2f + (size_t)n * 320 + h * 40;
    float s1 = 0.f, s2 = 0.f;
#pragma unroll
    for (int b = 0; b < 5; b++) {
        uint2 raw = *reinterpret_cast<const uint2*>(hr + b * 8);
        float h8[8];
        dec8(raw, h8);
#pragma unroll
        for (int j = 0; j < 8; j++) {
            int c = h * 40 + b * 8 + j;
            s1 = fmaf(h8[j], a2s[c], s1);
            s2 = fmaf(h8[j], a2d[c], s2);
        }
    }
    as2[t] = s1;
    ad2[t] = s2;
}

// ---------------- layer-2 aggregation + head-mean + bias + log_softmax ----------------

__global__ __launch_bounds__(256) void agg2_k(const u8* __restrict__ h2f,
                                              const float* __restrict__ as2, const float* __restrict__ ad2,
                                              const int* __restrict__ srcs, const int* __restrict__ rowstart,
                                              const float* __restrict__ b2, float* __restrict__ out, int Nn) {
    __shared__ float smem[4][320];
    int wave = threadIdx.x >> 6, lane = threadIdx.x & 63;
    int n = blockIdx.x * 4 + wave;
    bool active = (n < Nn);
    bool ld = active && (lane < 40);
    const int hl = lane / 5;
    float adl = ld ? ad2[n * 8 + hl] : 0.f;
    float acc[8] = {0, 0, 0, 0, 0, 0, 0, 0};
    float dsum = 0.f;
    if (ld) {
        const size_t loff = (size_t)lane * 8;
        int beg = rowstart[n], end = rowstart[n + 1];
        int i = beg;
        for (; i + 8 <= end; i += 8) {
            int s[8];
#pragma unroll
            for (int u = 0; u < 8; u++) s[u] = srcs[i + u];
            uint2 rw[8];
#pragma unroll
            for (int u = 0; u < 8; u++) rw[u] = *reinterpret_cast<const uint2*>(h2f + (size_t)s[u] * 320 + loff);
            float eg[8];
#pragma unroll
            for (int u = 0; u < 8; u++) eg[u] = as2[s[u] * 8 + hl];
            float p[8];
#pragma unroll
            for (int u = 0; u < 8; u++) { p[u] = lrelu_exp(eg[u] + adl); dsum += p[u]; }
#pragma unroll
            for (int u = 0; u < 8; u++) {
                float hv[8];
                dec8(rw[u], hv);
#pragma unroll
                for (int j = 0; j < 8; j++) acc[j] = fmaf(p[u], hv[j], acc[j]);
            }
        }
        for (; i + 4 <= end; i += 4) {
            int s[4];
#pragma unroll
            for (int u = 0; u < 4; u++) s[u] = srcs[i + u];
            uint2 rw[4];
#pragma unroll
            for (int u = 0; u < 4; u++) rw[u] = *reinterpret_cast<const uint2*>(h2f + (size_t)s[u] * 320 + loff);
#pragma unroll
            for (int u = 0; u < 4; u++) {
                float p = lrelu_exp(as2[s[u] * 8 + hl] + adl);
                dsum += p;
                float hv[8];
                dec8(rw[u], hv);
#pragma unroll
                for (int j = 0; j < 8; j++) acc[j] = fmaf(p, hv[j], acc[j]);
            }
        }
        for (; i < end; i++) {
            int s = srcs[i];
            uint2 raw = *reinterpret_cast<const uint2*>(h2f + (size_t)s * 320 + loff);
            float p = lrelu_exp(as2[s * 8 + hl] + adl);
            dsum += p;
            float hv[8];
            dec8(raw, hv);
#pragma unroll
            for (int j = 0; j < 8; j++) acc[j] = fmaf(p, hv[j], acc[j]);
        }
        float inv = 1.f / (dsum + 1e-16f);
#pragma unroll
        for (int j = 0; j < 8; j++) smem[wave][lane * 8 + j] = acc[j] * inv;
    }
    __syncthreads();
    if (active) {
        float v;
        if (lane < 40) {
            float ssum = 0.f;
#pragma unroll
            for (int h = 0; h < 8; h++) ssum += smem[wave][h * 40 + lane];
            v = ssum * 0.125f + b2[lane];
        } else {
            v = -INFINITY;
        }
        float m = v;
        for (int off = 32; off > 0; off >>= 1) m = fmaxf(m, __shfl_xor(m, off, 64));
        float ex = (lane < 40) ? __expf(v - m) : 0.f;
        float se = ex;
        for (int off = 32; off > 0; off >>= 1) se += __shfl_xor(se, off, 64);
        if (lane < 40) out[(size_t)n * 40 + lane] = v - m - __logf(se);
    }
}

// ---------------- launch ----------------

extern "C" void kernel_launch(void* const* d_in, const int* in_sizes, int n_in,
                              void* d_out, int out_size, void* d_ws, size_t ws_size,
                              hipStream_t stream) {
    const float* x   = (const float*)d_in[0];
    const int*   ei  = (const int*)d_in[1];
    const float* W0  = (const float*)d_in[3];
    const float* a0s = (const float*)d_in[4];
    const float* a0d = (const float*)d_in[5];
    const float* b0  = (const float*)d_in[6];
    const float* W2  = (const float*)d_in[7];
    const float* a2s = (const float*)d_in[8];
    const float* a2d = (const float*)d_in[9];
    const float* b2  = (const float*)d_in[10];
    float* out = (float*)d_out;

    const int Nn = in_sizes[0] / 256;   // 50000
    const int E  = in_sizes[1] / 2;     // 800000
    const int ET = E + Nn;

    size_t off = 0;
    auto carve = [&](size_t bytes) -> void* {
        void* p = (char*)d_ws + off;
        off += (bytes + 255) & ~(size_t)255;
        return p;
    };
    u16*   xb       = (u16*)carve((size_t)Nn * 256 * 2);
    u16*   W0b      = (u16*)carve((size_t)512 * 256 * 2);
    u16*   W2b      = (u16*)carve((size_t)320 * 64 * 2);
    u8*    h1f      = (u8*)carve((size_t)Nn * 512);       // 25.6 MB fp8
    u16*   x1b      = (u16*)carve((size_t)Nn * 64 * 2);
    u8*    h2f      = (u8*)carve((size_t)Nn * 320);       // 16 MB fp8
    float* as1      = (float*)carve((size_t)Nn * 8 * 4);
    float* ad1      = (float*)carve((size_t)Nn * 8 * 4);
    float* as2      = (float*)carve((size_t)Nn * 8 * 4);
    float* ad2      = (float*)carve((size_t)Nn * 8 * 4);
    int*   deg      = (int*)carve((size_t)Nn * 4);
    int*   cursor   = (int*)carve((size_t)Nn * 4);
    int*   rowstart = (int*)carve((size_t)(Nn + 1) * 4);
    int*   srcs     = (int*)carve((size_t)ET * 4);

    hipMemsetAsync(deg, 0, (size_t)Nn * 4, stream);
    hipMemsetAsync(cursor, 0, (size_t)Nn * 4, stream);
    hipMemsetAsync(as1, 0, (size_t)Nn * 8 * 4, stream);
    hipMemsetAsync(ad1, 0, (size_t)Nn * 8 * 4, stream);

    hist_k<<<(ET + 255) / 256, 256, 0, stream>>>(ei, deg, E, Nn);
    scan_k<<<1, 1024, 0, stream>>>(deg, rowstart, Nn, ET);
    scatter_k<<<(ET + 255) / 256, 256, 0, stream>>>(ei, rowstart, cursor, srcs, E, Nn);

    cast_k<<<(Nn * 256 / 4 + 255) / 256, 256, 0, stream>>>(x, xb, Nn * 256);
    cast_k<<<(512 * 256 / 4 + 255) / 256, 256, 0, stream>>>(W0, W0b, 512 * 256);
    cast_k<<<(320 * 64 / 4 + 255) / 256, 256, 0, stream>>>(W2, W2b, 320 * 64);

    // layer 1: GEMM + fused logits (fp32 acc), fp8 h1
    gemm_mfma<<<dim3((Nn + 127) / 128, 4), 256, 0, stream>>>(xb, W0b, h1f, Nn, 512, 256,
                                                             a0s, a0d, as1, ad1);
    agg1_k<<<(Nn + 3) / 4, 256, 0, stream>>>(h1f, as1, ad1, srcs, rowstart, b0, x1b, Nn);

    // layer 2: GEMM (no fused logits: heads not 64-aligned), fp8 h2
    gemm_mfma<<<dim3((Nn + 127) / 128, 3), 256, 0, stream>>>(x1b, W2b, h2f, Nn, 320, 64,
                                                             nullptr, nullptr, nullptr, nullptr);
    att2_k<<<(Nn * 8 + 255) / 256, 256, 0, stream>>>(h2f, a2s, a2d, as2, ad2, Nn);
    agg2_k<<<(Nn + 3) / 4, 256, 0, stream>>>(h2f, as2, ad2, srcs, rowstart, b2, out, Nn);
}

// Round 5
// 517.816 us; speedup vs baseline: 2.0965x; 1.0138x over previous
//
#include <hip/hip_runtime.h>
#include <hip/hip_bf16.h>
#include <math.h>

// GATNet round 5: coalesced fp8 C-store via LDS repack (fixes 2x write
// amplification + byte-store issue storm seen in round 4: WRITE 50MB for a
// 25.6MB tensor, MfmaUtil 5%), casts folded into GEMM staging (no cast
// kernels, no xb/W0b/W2b buffers). Aggs unchanged (at L2-fill floor).

#define NEG_SLOPE 0.2f

typedef short v8s __attribute__((ext_vector_type(8)));
typedef float v4f __attribute__((ext_vector_type(4)));
typedef float v2f __attribute__((ext_vector_type(2)));
typedef unsigned short u16;
typedef unsigned int u32;
typedef unsigned char u8;

__device__ __forceinline__ u16 f2bf(float f) {
    union { float f; u32 u; } v; v.f = f;
    u32 r = v.u + 0x7fffu + ((v.u >> 16) & 1u);
    return (u16)(r >> 16);
}
__device__ __forceinline__ float lrelu_exp(float e) {
    e = (e > 0.f) ? e : NEG_SLOPE * e;
    return __expf(e);
}
__device__ __forceinline__ void dec8(uint2 r, float* h) {
    v2f a = __builtin_amdgcn_cvt_pk_f32_fp8(r.x, false);
    v2f b = __builtin_amdgcn_cvt_pk_f32_fp8(r.x, true);
    v2f c = __builtin_amdgcn_cvt_pk_f32_fp8(r.y, false);
    v2f d = __builtin_amdgcn_cvt_pk_f32_fp8(r.y, true);
    h[0] = a.x; h[1] = a.y; h[2] = b.x; h[3] = b.y;
    h[4] = c.x; h[5] = c.y; h[6] = d.x; h[7] = d.y;
}
__device__ __forceinline__ u8 enc8(float v) {
    u32 p = __builtin_amdgcn_cvt_pk_fp8_f32(v, v, 0u, false);
    return (u8)(p & 0xffu);
}

// ---------------- CSR build ----------------

__global__ __launch_bounds__(256) void hist_k(const int* __restrict__ ei, int* __restrict__ deg,
                                              int E, int Nn) {
    int e = blockIdx.x * 256 + threadIdx.x;
    int ET = E + Nn;
    if (e >= ET) return;
    int d = (e < E) ? ei[E + e] : (e - E);
    atomicAdd(&deg[d], 1);
}

__global__ __launch_bounds__(1024) void scan_k(const int* __restrict__ deg, int* __restrict__ rowstart,
                                               int n, int total) {
    __shared__ int wsum[16];
    int t = threadIdx.x;
    int chunk = (n + 1023) / 1024;
    int base = t * chunk;
    int s = 0;
    for (int i = 0; i < chunk; i++) {
        int idx = base + i;
        if (idx < n) s += deg[idx];
    }
    int v = s;
    int lane = t & 63;
    for (int off = 1; off < 64; off <<= 1) {
        int u = __shfl_up(v, off, 64);
        if (lane >= off) v += u;
    }
    int wid = t >> 6;
    if (lane == 63) wsum[wid] = v;
    __syncthreads();
    if (t < 16) {
        int w = wsum[t];
        for (int off = 1; off < 16; off <<= 1) {
            int u = __shfl_up(w, off, 64);
            if (t >= off) w += u;
        }
        wsum[t] = w;
    }
    __syncthreads();
    int wpre = (wid > 0) ? wsum[wid - 1] : 0;
    int excl = wpre + v - s;
    for (int i = 0; i < chunk; i++) {
        int idx = base + i;
        if (idx < n) { rowstart[idx] = excl; excl += deg[idx]; }
    }
    if (t == 1023) rowstart[n] = total;
}

__global__ __launch_bounds__(256) void scatter_k(const int* __restrict__ ei,
                                                 const int* __restrict__ rowstart,
                                                 int* __restrict__ cursor,
                                                 int* __restrict__ srcs, int E, int Nn) {
    int e = blockIdx.x * 256 + threadIdx.x;
    int ET = E + Nn;
    if (e >= ET) return;
    int s, d;
    if (e < E) { s = ei[e]; d = ei[E + e]; }
    else       { s = e - E; d = e - E; }
    int pos = atomicAdd(&cursor[d], 1);
    srcs[rowstart[d] + pos] = s;
}

// ---------------- bf16 MFMA GEMM -> fp8 C (LDS-repacked coalesced store) ----------------
// C[M,Nc] = A[M,K]*B[Nc,K]^T. A is fp32 (AF32) or bf16; B is fp32; both
// converted to bf16 during LDS staging. If as_out!=null, fused attention
// logits from fp32 accumulators (head = col>>6, layer-1 only).

template<bool AF32>
__global__ __launch_bounds__(256) void gemm_mfma(const void* __restrict__ Ap,
                                                 const float* __restrict__ Bf,
                                                 u8* __restrict__ Cf, int M, int Nc, int K,
                                                 const float* __restrict__ avs_vec,
                                                 const float* __restrict__ avd_vec,
                                                 float* as_out, float* ad_out) {
    __shared__ __align__(16) u8 lds[20480];
    u16 (*As)[40] = reinterpret_cast<u16(*)[40]>(lds);
    u16 (*Bs)[40] = reinterpret_cast<u16(*)[40]>(lds + 10240);
    const int t = threadIdx.x;
    const int m0 = blockIdx.x * 128;
    const int n0 = blockIdx.y * 128;
    const int w = t >> 6, lane = t & 63;
    const int wr = (w >> 1) * 64, wc = (w & 1) * 64;
    const int q = lane >> 4, l16 = lane & 15;
    const int r0 = t >> 2;
    const int c8 = (t & 3) * 8;

    v4f acc[4][4];
#pragma unroll
    for (int i = 0; i < 4; i++)
#pragma unroll
        for (int j = 0; j < 4; j++) acc[i][j] = (v4f){0.f, 0.f, 0.f, 0.f};

    for (int kt = 0; kt < K; kt += 32) {
#pragma unroll
        for (int p = 0; p < 2; p++) {
            int r = r0 + p * 64;
            int gm = m0 + r;
            if (AF32) {
                const float* A = (const float*)Ap;
                u16 a8[8] = {0, 0, 0, 0, 0, 0, 0, 0};
                if (gm < M) {
                    float4 v0 = *reinterpret_cast<const float4*>(A + (size_t)gm * K + kt + c8);
                    float4 v1 = *reinterpret_cast<const float4*>(A + (size_t)gm * K + kt + c8 + 4);
                    a8[0] = f2bf(v0.x); a8[1] = f2bf(v0.y); a8[2] = f2bf(v0.z); a8[3] = f2bf(v0.w);
                    a8[4] = f2bf(v1.x); a8[5] = f2bf(v1.y); a8[6] = f2bf(v1.z); a8[7] = f2bf(v1.w);
                }
                *reinterpret_cast<uint4*>(&As[r][c8]) = *reinterpret_cast<const uint4*>(a8);
            } else {
                const u16* A = (const u16*)Ap;
                uint4 va = make_uint4(0u, 0u, 0u, 0u);
                if (gm < M) va = *reinterpret_cast<const uint4*>(A + (size_t)gm * K + kt + c8);
                *reinterpret_cast<uint4*>(&As[r][c8]) = va;
            }
            int gn = n0 + r;
            u16 b8[8] = {0, 0, 0, 0, 0, 0, 0, 0};
            if (gn < Nc) {
                float4 w0 = *reinterpret_cast<const float4*>(Bf + (size_t)gn * K + kt + c8);
                float4 w1 = *reinterpret_cast<const float4*>(Bf + (size_t)gn * K + kt + c8 + 4);
                b8[0] = f2bf(w0.x); b8[1] = f2bf(w0.y); b8[2] = f2bf(w0.z); b8[3] = f2bf(w0.w);
                b8[4] = f2bf(w1.x); b8[5] = f2bf(w1.y); b8[6] = f2bf(w1.z); b8[7] = f2bf(w1.w);
            }
            *reinterpret_cast<uint4*>(&Bs[r][c8]) = *reinterpret_cast<const uint4*>(b8);
        }
        __syncthreads();
        v8s af[4], bf[4];
#pragma unroll
        for (int i = 0; i < 4; i++) af[i] = *reinterpret_cast<const v8s*>(&As[wr + i * 16 + l16][q * 8]);
#pragma unroll
        for (int j = 0; j < 4; j++) bf[j] = *reinterpret_cast<const v8s*>(&Bs[wc + j * 16 + l16][q * 8]);
#pragma unroll
        for (int i = 0; i < 4; i++)
#pragma unroll
            for (int j = 0; j < 4; j++)
                acc[i][j] = __builtin_amdgcn_mfma_f32_16x16x32_bf16(af[i], bf[j], acc[i][j], 0, 0, 0);
        __syncthreads();
    }

    const bool do_att = (as_out != nullptr);
    float avs[4], avd[4];
    if (do_att) {
#pragma unroll
        for (int j = 0; j < 4; j++) {
            int gn = n0 + wc + j * 16 + l16;
            avs[j] = (gn < Nc) ? avs_vec[gn] : 0.f;
            avd[j] = (gn < Nc) ? avd_vec[gn] : 0.f;
        }
    }
    const int head = (n0 + wc) >> 6;

    // encode C tile into LDS (row stride 144B, 16B-aligned rows), fused att
    u8* Cs = lds;
#pragma unroll
    for (int i = 0; i < 4; i++) {
#pragma unroll
        for (int r = 0; r < 4; r++) {
            int row = wr + i * 16 + q * 4 + r;
#pragma unroll
            for (int j = 0; j < 4; j++)
                Cs[row * 144 + wc + j * 16 + l16] = enc8(acc[i][j][r]);
            if (do_att) {
                int gm = m0 + row;
                float ps = 0.f, pd = 0.f;
#pragma unroll
                for (int j = 0; j < 4; j++) {
                    float v = acc[i][j][r];
                    ps = fmaf(v, avs[j], ps);
                    pd = fmaf(v, avd[j], pd);
                }
#pragma unroll
                for (int m = 1; m < 16; m <<= 1) {
                    ps += __shfl_xor(ps, m, 64);
                    pd += __shfl_xor(pd, m, 64);
                }
                if (l16 == 0 && gm < M) {
                    atomicAdd(&as_out[gm * 8 + head], ps);
                    atomicAdd(&ad_out[gm * 8 + head], pd);
                }
            }
        }
    }
    __syncthreads();
    // coalesced 16B stores: 128 rows x 8 chunks
#pragma unroll
    for (int it = 0; it < 4; it++) {
        int idx = it * 256 + t;
        int row = idx >> 3, ch = idx & 7;
        int gm = m0 + row, gn = n0 + ch * 16;
        if (gm < M && gn < Nc)
            *reinterpret_cast<uint4*>(Cf + (size_t)gm * Nc + gn) =
                *reinterpret_cast<const uint4*>(&Cs[row * 144 + ch * 16]);
    }
}

// ---------------- layer-1 aggregation: wave/dst, 8-deep fp8 gather, bf16 x1 out ----------------

__global__ __launch_bounds__(256) void agg1_k(const u8* __restrict__ h1f,
                                              const float* __restrict__ as1, const float* __restrict__ ad1,
                                              const int* __restrict__ srcs, const int* __restrict__ rowstart,
                                              const float* __restrict__ b0, u16* __restrict__ x1b, int Nn) {
    int wave = threadIdx.x >> 6, lane = threadIdx.x & 63;
    int n = blockIdx.x * 4 + wave;
    if (n >= Nn) return;
    const int hl = lane >> 3;
    const float adl = ad1[n * 8 + hl];
    const size_t loff = (size_t)lane * 8;
    float acc[8] = {0, 0, 0, 0, 0, 0, 0, 0};
    float dsum = 0.f;
    int beg = rowstart[n], end = rowstart[n + 1];
    int i = beg;
    for (; i + 8 <= end; i += 8) {
        int s[8];
#pragma unroll
        for (int u = 0; u < 8; u++) s[u] = srcs[i + u];
        uint2 rw[8];
#pragma unroll
        for (int u = 0; u < 8; u++) rw[u] = *reinterpret_cast<const uint2*>(h1f + (size_t)s[u] * 512 + loff);
        float eg[8];
#pragma unroll
        for (int u = 0; u < 8; u++) eg[u] = as1[s[u] * 8 + hl];
        float p[8];
#pragma unroll
        for (int u = 0; u < 8; u++) { p[u] = lrelu_exp(eg[u] + adl); dsum += p[u]; }
#pragma unroll
        for (int u = 0; u < 8; u++) {
            float hv[8];
            dec8(rw[u], hv);
#pragma unroll
            for (int j = 0; j < 8; j++) acc[j] = fmaf(p[u], hv[j], acc[j]);
        }
    }
    for (; i + 4 <= end; i += 4) {
        int s[4];
#pragma unroll
        for (int u = 0; u < 4; u++) s[u] = srcs[i + u];
        uint2 rw[4];
#pragma unroll
        for (int u = 0; u < 4; u++) rw[u] = *reinterpret_cast<const uint2*>(h1f + (size_t)s[u] * 512 + loff);
#pragma unroll
        for (int u = 0; u < 4; u++) {
            float p = lrelu_exp(as1[s[u] * 8 + hl] + adl);
            dsum += p;
            float hv[8];
            dec8(rw[u], hv);
#pragma unroll
            for (int j = 0; j < 8; j++) acc[j] = fmaf(p, hv[j], acc[j]);
        }
    }
    for (; i < end; i++) {
        int s = srcs[i];
        uint2 raw = *reinterpret_cast<const uint2*>(h1f + (size_t)s * 512 + loff);
        float p = lrelu_exp(as1[s * 8 + hl] + adl);
        dsum += p;
        float hv[8];
        dec8(raw, hv);
#pragma unroll
        for (int j = 0; j < 8; j++) acc[j] = fmaf(p, hv[j], acc[j]);
    }
    float inv = 1.f / (dsum + 1e-16f);
    float r[8];
#pragma unroll
    for (int j = 0; j < 8; j++) r[j] = acc[j] * inv;
#pragma unroll
    for (int j = 0; j < 8; j++) {
        r[j] += __shfl_xor(r[j], 8, 64);
        r[j] += __shfl_xor(r[j], 16, 64);
        r[j] += __shfl_xor(r[j], 32, 64);
    }
    if (lane < 8) {
        u16 o[8];
#pragma unroll
        for (int j = 0; j < 8; j++) {
            float v = r[j] * 0.125f + b0[lane * 8 + j];
            o[j] = f2bf((v > 0.f) ? v : 0.f);
        }
        *reinterpret_cast<uint4*>(x1b + (size_t)n * 64 + lane * 8) =
            *reinterpret_cast<const uint4*>(o);
    }
}

// ---------------- layer-2 attention logits ----------------

__global__ __launch_bounds__(256) void att2_k(const u8* __restrict__ h2f,
                                              const float* __restrict__ a2s, const float* __restrict__ a2d,
                                              float* __restrict__ as2, float* __restrict__ ad2, int Nn) {
    int t = blockIdx.x * 256 + threadIdx.x;
    if (t >= Nn * 8) return;
    int n = t >> 3, h = t & 7;
    const u8* hr = h2f + (size_t)n * 320 + h * 40;
    float s1 = 0.f, s2 = 0.f;
#pragma unroll
    for (int b = 0; b < 5; b++) {
        uint2 raw = *reinterpret_cast<const uint2*>(hr + b * 8);
        float h8[8];
        dec8(raw, h8);
#pragma unroll
        for (int j = 0; j < 8; j++) {
            int c = h * 40 + b * 8 + j;
            s1 = fmaf(h8[j], a2s[c], s1);
            s2 = fmaf(h8[j], a2d[c], s2);
        }
    }
    as2[t] = s1;
    ad2[t] = s2;
}

// ---------------- layer-2 aggregation + head-mean + bias + log_softmax ----------------

__global__ __launch_bounds__(256) void agg2_k(const u8* __restrict__ h2f,
                                              const float* __restrict__ as2, const float* __restrict__ ad2,
                                              const int* __restrict__ srcs, const int* __restrict__ rowstart,
                                              const float* __restrict__ b2, float* __restrict__ out, int Nn) {
    __shared__ float smem[4][320];
    int wave = threadIdx.x >> 6, lane = threadIdx.x & 63;
    int n = blockIdx.x * 4 + wave;
    bool active = (n < Nn);
    bool ld = active && (lane < 40);
    const int hl = lane / 5;
    float adl = ld ? ad2[n * 8 + hl] : 0.f;
    float acc[8] = {0, 0, 0, 0, 0, 0, 0, 0};
    float dsum = 0.f;
    if (ld) {
        const size_t loff = (size_t)lane * 8;
        int beg = rowstart[n], end = rowstart[n + 1];
        int i = beg;
        for (; i + 8 <= end; i += 8) {
            int s[8];
#pragma unroll
            for (int u = 0; u < 8; u++) s[u] = srcs[i + u];
            uint2 rw[8];
#pragma unroll
            for (int u = 0; u < 8; u++) rw[u] = *reinterpret_cast<const uint2*>(h2f + (size_t)s[u] * 320 + loff);
            float eg[8];
#pragma unroll
            for (int u = 0; u < 8; u++) eg[u] = as2[s[u] * 8 + hl];
            float p[8];
#pragma unroll
            for (int u = 0; u < 8; u++) { p[u] = lrelu_exp(eg[u] + adl); dsum += p[u]; }
#pragma unroll
            for (int u = 0; u < 8; u++) {
                float hv[8];
                dec8(rw[u], hv);
#pragma unroll
                for (int j = 0; j < 8; j++) acc[j] = fmaf(p[u], hv[j], acc[j]);
            }
        }
        for (; i + 4 <= end; i += 4) {
            int s[4];
#pragma unroll
            for (int u = 0; u < 4; u++) s[u] = srcs[i + u];
            uint2 rw[4];
#pragma unroll
            for (int u = 0; u < 4; u++) rw[u] = *reinterpret_cast<const uint2*>(h2f + (size_t)s[u] * 320 + loff);
#pragma unroll
            for (int u = 0; u < 4; u++) {
                float p = lrelu_exp(as2[s[u] * 8 + hl] + adl);
                dsum += p;
                float hv[8];
                dec8(rw[u], hv);
#pragma unroll
                for (int j = 0; j < 8; j++) acc[j] = fmaf(p, hv[j], acc[j]);
            }
        }
        for (; i < end; i++) {
            int s = srcs[i];
            uint2 raw = *reinterpret_cast<const uint2*>(h2f + (size_t)s * 320 + loff);
            float p = lrelu_exp(as2[s * 8 + hl] + adl);
            dsum += p;
            float hv[8];
            dec8(raw, hv);
#pragma unroll
            for (int j = 0; j < 8; j++) acc[j] = fmaf(p, hv[j], acc[j]);
        }
        float inv = 1.f / (dsum + 1e-16f);
#pragma unroll
        for (int j = 0; j < 8; j++) smem[wave][lane * 8 + j] = acc[j] * inv;
    }
    __syncthreads();
    if (active) {
        float v;
        if (lane < 40) {
            float ssum = 0.f;
#pragma unroll
            for (int h = 0; h < 8; h++) ssum += smem[wave][h * 40 + lane];
            v = ssum * 0.125f + b2[lane];
        } else {
            v = -INFINITY;
        }
        float m = v;
        for (int off = 32; off > 0; off >>= 1) m = fmaxf(m, __shfl_xor(m, off, 64));
        float ex = (lane < 40) ? __expf(v - m) : 0.f;
        float se = ex;
        for (int off = 32; off > 0; off >>= 1) se += __shfl_xor(se, off, 64);
        if (lane < 40) out[(size_t)n * 40 + lane] = v - m - __logf(se);
    }
}

// ---------------- launch ----------------

extern "C" void kernel_launch(void* const* d_in, const int* in_sizes, int n_in,
                              void* d_out, int out_size, void* d_ws, size_t ws_size,
                              hipStream_t stream) {
    const float* x   = (const float*)d_in[0];
    const int*   ei  = (const int*)d_in[1];
    const float* W0  = (const float*)d_in[3];
    const float* a0s = (const float*)d_in[4];
    const float* a0d = (const float*)d_in[5];
    const float* b0  = (const float*)d_in[6];
    const float* W2  = (const float*)d_in[7];
    const float* a2s = (const float*)d_in[8];
    const float* a2d = (const float*)d_in[9];
    const float* b2  = (const float*)d_in[10];
    float* out = (float*)d_out;

    const int Nn = in_sizes[0] / 256;   // 50000
    const int E  = in_sizes[1] / 2;     // 800000
    const int ET = E + Nn;

    size_t off = 0;
    auto carve = [&](size_t bytes) -> void* {
        void* p = (char*)d_ws + off;
        off += (bytes + 255) & ~(size_t)255;
        return p;
    };
    u8*    h1f      = (u8*)carve((size_t)Nn * 512);       // 25.6 MB fp8
    u16*   x1b      = (u16*)carve((size_t)Nn * 64 * 2);
    u8*    h2f      = (u8*)carve((size_t)Nn * 320);       // 16 MB fp8
    float* as1      = (float*)carve((size_t)Nn * 8 * 4);
    float* ad1      = (float*)carve((size_t)Nn * 8 * 4);
    float* as2      = (float*)carve((size_t)Nn * 8 * 4);
    float* ad2      = (float*)carve((size_t)Nn * 8 * 4);
    int*   deg      = (int*)carve((size_t)Nn * 4);
    int*   cursor   = (int*)carve((size_t)Nn * 4);
    int*   rowstart = (int*)carve((size_t)(Nn + 1) * 4);
    int*   srcs     = (int*)carve((size_t)ET * 4);

    hipMemsetAsync(deg, 0, (size_t)Nn * 4, stream);
    hipMemsetAsync(cursor, 0, (size_t)Nn * 4, stream);
    hipMemsetAsync(as1, 0, (size_t)Nn * 8 * 4, stream);
    hipMemsetAsync(ad1, 0, (size_t)Nn * 8 * 4, stream);

    hist_k<<<(ET + 255) / 256, 256, 0, stream>>>(ei, deg, E, Nn);
    scan_k<<<1, 1024, 0, stream>>>(deg, rowstart, Nn, ET);
    scatter_k<<<(ET + 255) / 256, 256, 0, stream>>>(ei, rowstart, cursor, srcs, E, Nn);

    // layer 1: GEMM (fp32 A conversion in staging) + fused logits, fp8 h1
    gemm_mfma<true><<<dim3((Nn + 127) / 128, 4), 256, 0, stream>>>(
        x, W0, h1f, Nn, 512, 256, a0s, a0d, as1, ad1);
    agg1_k<<<(Nn + 3) / 4, 256, 0, stream>>>(h1f, as1, ad1, srcs, rowstart, b0, x1b, Nn);

    // layer 2: GEMM (bf16 A), fp8 h2
    gemm_mfma<false><<<dim3((Nn + 127) / 128, 3), 256, 0, stream>>>(
        x1b, W2, h2f, Nn, 320, 64, nullptr, nullptr, nullptr, nullptr);
    att2_k<<<(Nn * 8 + 255) / 256, 256, 0, stream>>>(h2f, a2s, a2d, as2, ad2, Nn);
    agg2_k<<<(Nn + 3) / 4, 256, 0, stream>>>(h2f, as2, ad2, srcs, rowstart, b2, out, Nn);
}

// Round 6
// 490.221 us; speedup vs baseline: 2.2145x; 1.0563x over previous
//
#include <hip/hip_runtime.h>
#include <hip/hip_bf16.h>
#include <math.h>

// GATNet round 6: removed device-scope atomicAdd from gemm1's fused-logit
// epilogue (each head's 64 channels live entirely in one wave half-slab ->
// the 16-lane-reduced dot is complete -> plain store). Round-5 counters
// showed the atomics as ~25MB extra FETCH + ~25MB extra WRITE (RMW beyond
// the non-coherent L2s) and the pipes all <20% busy. A-path back to bf16
// via one-time cast (round-5 fp32 staging doubled FETCH for no gain).

#define NEG_SLOPE 0.2f

typedef short v8s __attribute__((ext_vector_type(8)));
typedef float v4f __attribute__((ext_vector_type(4)));
typedef float v2f __attribute__((ext_vector_type(2)));
typedef unsigned short u16;
typedef unsigned int u32;
typedef unsigned char u8;

__device__ __forceinline__ u16 f2bf(float f) {
    union { float f; u32 u; } v; v.f = f;
    u32 r = v.u + 0x7fffu + ((v.u >> 16) & 1u);
    return (u16)(r >> 16);
}
__device__ __forceinline__ float lrelu_exp(float e) {
    e = (e > 0.f) ? e : NEG_SLOPE * e;
    return __expf(e);
}
__device__ __forceinline__ void dec8(uint2 r, float* h) {
    v2f a = __builtin_amdgcn_cvt_pk_f32_fp8(r.x, false);
    v2f b = __builtin_amdgcn_cvt_pk_f32_fp8(r.x, true);
    v2f c = __builtin_amdgcn_cvt_pk_f32_fp8(r.y, false);
    v2f d = __builtin_amdgcn_cvt_pk_f32_fp8(r.y, true);
    h[0] = a.x; h[1] = a.y; h[2] = b.x; h[3] = b.y;
    h[4] = c.x; h[5] = c.y; h[6] = d.x; h[7] = d.y;
}
__device__ __forceinline__ u8 enc8(float v) {
    u32 p = __builtin_amdgcn_cvt_pk_fp8_f32(v, v, 0u, false);
    return (u8)(p & 0xffu);
}

// ---------------- CSR build ----------------

__global__ __launch_bounds__(256) void hist_k(const int* __restrict__ ei, int* __restrict__ deg,
                                              int E, int Nn) {
    int e = blockIdx.x * 256 + threadIdx.x;
    int ET = E + Nn;
    if (e >= ET) return;
    int d = (e < E) ? ei[E + e] : (e - E);
    atomicAdd(&deg[d], 1);
}

__global__ __launch_bounds__(1024) void scan_k(const int* __restrict__ deg, int* __restrict__ rowstart,
                                               int n, int total) {
    __shared__ int wsum[16];
    int t = threadIdx.x;
    int chunk = (n + 1023) / 1024;
    int base = t * chunk;
    int s = 0;
    for (int i = 0; i < chunk; i++) {
        int idx = base + i;
        if (idx < n) s += deg[idx];
    }
    int v = s;
    int lane = t & 63;
    for (int off = 1; off < 64; off <<= 1) {
        int u = __shfl_up(v, off, 64);
        if (lane >= off) v += u;
    }
    int wid = t >> 6;
    if (lane == 63) wsum[wid] = v;
    __syncthreads();
    if (t < 16) {
        int w = wsum[t];
        for (int off = 1; off < 16; off <<= 1) {
            int u = __shfl_up(w, off, 64);
            if (t >= off) w += u;
        }
        wsum[t] = w;
    }
    __syncthreads();
    int wpre = (wid > 0) ? wsum[wid - 1] : 0;
    int excl = wpre + v - s;
    for (int i = 0; i < chunk; i++) {
        int idx = base + i;
        if (idx < n) { rowstart[idx] = excl; excl += deg[idx]; }
    }
    if (t == 1023) rowstart[n] = total;
}

__global__ __launch_bounds__(256) void scatter_k(const int* __restrict__ ei,
                                                 const int* __restrict__ rowstart,
                                                 int* __restrict__ cursor,
                                                 int* __restrict__ srcs, int E, int Nn) {
    int e = blockIdx.x * 256 + threadIdx.x;
    int ET = E + Nn;
    if (e >= ET) return;
    int s, d;
    if (e < E) { s = ei[e]; d = ei[E + e]; }
    else       { s = e - E; d = e - E; }
    int pos = atomicAdd(&cursor[d], 1);
    srcs[rowstart[d] + pos] = s;
}

// ---------------- fp32 -> bf16 cast ----------------

__global__ __launch_bounds__(256) void cast_k(const float* __restrict__ in, u16* __restrict__ out, int n) {
    int i = (blockIdx.x * 256 + threadIdx.x) * 4;
    if (i + 3 < n) {
        float4 v = *reinterpret_cast<const float4*>(in + i);
        ushort4 o;
        o.x = f2bf(v.x); o.y = f2bf(v.y); o.z = f2bf(v.z); o.w = f2bf(v.w);
        *reinterpret_cast<ushort4*>(out + i) = o;
    } else {
        for (int j = i; j < n; j++) out[j] = f2bf(in[j]);
    }
}

// ---------------- bf16 MFMA GEMM -> fp8 C (coalesced LDS-repacked store) ----------------
// C[M,Nc] = A[M,K]*B[Nc,K]^T. A bf16; B fp32 converted during staging.
// If as_out!=null: fused layer-1 attention logits, written with PLAIN
// stores (head = col>>6; each head's 64 cols lie in one wave half-slab,
// so the 16-lane-reduced dot is the complete logit — no atomics).

__global__ __launch_bounds__(256) void gemm_mfma(const u16* __restrict__ Ab,
                                                 const float* __restrict__ Bf,
                                                 u8* __restrict__ Cf, int M, int Nc, int K,
                                                 const float* __restrict__ avs_vec,
                                                 const float* __restrict__ avd_vec,
                                                 float* as_out, float* ad_out) {
    __shared__ __align__(16) u8 lds[20480];
    u16 (*As)[40] = reinterpret_cast<u16(*)[40]>(lds);
    u16 (*Bs)[40] = reinterpret_cast<u16(*)[40]>(lds + 10240);
    const int t = threadIdx.x;
    const int m0 = blockIdx.x * 128;
    const int n0 = blockIdx.y * 128;
    const int w = t >> 6, lane = t & 63;
    const int wr = (w >> 1) * 64, wc = (w & 1) * 64;
    const int q = lane >> 4, l16 = lane & 15;
    const int r0 = t >> 2;
    const int c8 = (t & 3) * 8;

    v4f acc[4][4];
#pragma unroll
    for (int i = 0; i < 4; i++)
#pragma unroll
        for (int j = 0; j < 4; j++) acc[i][j] = (v4f){0.f, 0.f, 0.f, 0.f};

    for (int kt = 0; kt < K; kt += 32) {
#pragma unroll
        for (int p = 0; p < 2; p++) {
            int r = r0 + p * 64;
            int gm = m0 + r;
            uint4 va = make_uint4(0u, 0u, 0u, 0u);
            if (gm < M) va = *reinterpret_cast<const uint4*>(Ab + (size_t)gm * K + kt + c8);
            *reinterpret_cast<uint4*>(&As[r][c8]) = va;
            int gn = n0 + r;
            u16 b8[8] = {0, 0, 0, 0, 0, 0, 0, 0};
            if (gn < Nc) {
                float4 w0 = *reinterpret_cast<const float4*>(Bf + (size_t)gn * K + kt + c8);
                float4 w1 = *reinterpret_cast<const float4*>(Bf + (size_t)gn * K + kt + c8 + 4);
                b8[0] = f2bf(w0.x); b8[1] = f2bf(w0.y); b8[2] = f2bf(w0.z); b8[3] = f2bf(w0.w);
                b8[4] = f2bf(w1.x); b8[5] = f2bf(w1.y); b8[6] = f2bf(w1.z); b8[7] = f2bf(w1.w);
            }
            *reinterpret_cast<uint4*>(&Bs[r][c8]) = *reinterpret_cast<const uint4*>(b8);
        }
        __syncthreads();
        v8s af[4], bf[4];
#pragma unroll
        for (int i = 0; i < 4; i++) af[i] = *reinterpret_cast<const v8s*>(&As[wr + i * 16 + l16][q * 8]);
#pragma unroll
        for (int j = 0; j < 4; j++) bf[j] = *reinterpret_cast<const v8s*>(&Bs[wc + j * 16 + l16][q * 8]);
#pragma unroll
        for (int i = 0; i < 4; i++)
#pragma unroll
            for (int j = 0; j < 4; j++)
                acc[i][j] = __builtin_amdgcn_mfma_f32_16x16x32_bf16(af[i], bf[j], acc[i][j], 0, 0, 0);
        __syncthreads();
    }

    const bool do_att = (as_out != nullptr);
    float avs[4], avd[4];
    if (do_att) {
#pragma unroll
        for (int j = 0; j < 4; j++) {
            int gn = n0 + wc + j * 16 + l16;
            avs[j] = (gn < Nc) ? avs_vec[gn] : 0.f;
            avd[j] = (gn < Nc) ? avd_vec[gn] : 0.f;
        }
    }
    const int head = (n0 + wc) >> 6;

    // encode C tile into LDS (row stride 144B), fused logits via plain store
    u8* Cs = lds;
#pragma unroll
    for (int i = 0; i < 4; i++) {
#pragma unroll
        for (int r = 0; r < 4; r++) {
            int row = wr + i * 16 + q * 4 + r;
#pragma unroll
            for (int j = 0; j < 4; j++)
                Cs[row * 144 + wc + j * 16 + l16] = enc8(acc[i][j][r]);
            if (do_att) {
                int gm = m0 + row;
                float ps = 0.f, pd = 0.f;
#pragma unroll
                for (int j = 0; j < 4; j++) {
                    float v = acc[i][j][r];
                    ps = fmaf(v, avs[j], ps);
                    pd = fmaf(v, avd[j], pd);
                }
#pragma unroll
                for (int m = 1; m < 16; m <<= 1) {
                    ps += __shfl_xor(ps, m, 64);
                    pd += __shfl_xor(pd, m, 64);
                }
                if (l16 == 0 && gm < M) {
                    as_out[gm * 8 + head] = ps;   // complete dot: no atomics
                    ad_out[gm * 8 + head] = pd;
                }
            }
        }
    }
    __syncthreads();
#pragma unroll
    for (int it = 0; it < 4; it++) {
        int idx = it * 256 + t;
        int row = idx >> 3, ch = idx & 7;
        int gm = m0 + row, gn = n0 + ch * 16;
        if (gm < M && gn < Nc)
            *reinterpret_cast<uint4*>(Cf + (size_t)gm * Nc + gn) =
                *reinterpret_cast<const uint4*>(&Cs[row * 144 + ch * 16]);
    }
}

// ---------------- layer-1 aggregation: wave/dst, 8-deep fp8 gather, bf16 x1 out ----------------

__global__ __launch_bounds__(256) void agg1_k(const u8* __restrict__ h1f,
                                              const float* __restrict__ as1, const float* __restrict__ ad1,
                                              const int* __restrict__ srcs, const int* __restrict__ rowstart,
                                              const float* __restrict__ b0, u16* __restrict__ x1b, int Nn) {
    int wave = threadIdx.x >> 6, lane = threadIdx.x & 63;
    int n = blockIdx.x * 4 + wave;
    if (n >= Nn) return;
    const int hl = lane >> 3;
    const float adl = ad1[n * 8 + hl];
    const size_t loff = (size_t)lane * 8;
    float acc[8] = {0, 0, 0, 0, 0, 0, 0, 0};
    float dsum = 0.f;
    int beg = rowstart[n], end = rowstart[n + 1];
    int i = beg;
    for (; i + 8 <= end; i += 8) {
        int s[8];
#pragma unroll
        for (int u = 0; u < 8; u++) s[u] = srcs[i + u];
        uint2 rw[8];
#pragma unroll
        for (int u = 0; u < 8; u++) rw[u] = *reinterpret_cast<const uint2*>(h1f + (size_t)s[u] * 512 + loff);
        float eg[8];
#pragma unroll
        for (int u = 0; u < 8; u++) eg[u] = as1[s[u] * 8 + hl];
        float p[8];
#pragma unroll
        for (int u = 0; u < 8; u++) { p[u] = lrelu_exp(eg[u] + adl); dsum += p[u]; }
#pragma unroll
        for (int u = 0; u < 8; u++) {
            float hv[8];
            dec8(rw[u], hv);
#pragma unroll
            for (int j = 0; j < 8; j++) acc[j] = fmaf(p[u], hv[j], acc[j]);
        }
    }
    for (; i + 4 <= end; i += 4) {
        int s[4];
#pragma unroll
        for (int u = 0; u < 4; u++) s[u] = srcs[i + u];
        uint2 rw[4];
#pragma unroll
        for (int u = 0; u < 4; u++) rw[u] = *reinterpret_cast<const uint2*>(h1f + (size_t)s[u] * 512 + loff);
#pragma unroll
        for (int u = 0; u < 4; u++) {
            float p = lrelu_exp(as1[s[u] * 8 + hl] + adl);
            dsum += p;
            float hv[8];
            dec8(rw[u], hv);
#pragma unroll
            for (int j = 0; j < 8; j++) acc[j] = fmaf(p, hv[j], acc[j]);
        }
    }
    for (; i < end; i++) {
        int s = srcs[i];
        uint2 raw = *reinterpret_cast<const uint2*>(h1f + (size_t)s * 512 + loff);
        float p = lrelu_exp(as1[s * 8 + hl] + adl);
        dsum += p;
        float hv[8];
        dec8(raw, hv);
#pragma unroll
        for (int j = 0; j < 8; j++) acc[j] = fmaf(p, hv[j], acc[j]);
    }
    float inv = 1.f / (dsum + 1e-16f);
    float r[8];
#pragma unroll
    for (int j = 0; j < 8; j++) r[j] = acc[j] * inv;
#pragma unroll
    for (int j = 0; j < 8; j++) {
        r[j] += __shfl_xor(r[j], 8, 64);
        r[j] += __shfl_xor(r[j], 16, 64);
        r[j] += __shfl_xor(r[j], 32, 64);
    }
    if (lane < 8) {
        u16 o[8];
#pragma unroll
        for (int j = 0; j < 8; j++) {
            float v = r[j] * 0.125f + b0[lane * 8 + j];
            o[j] = f2bf((v > 0.f) ? v : 0.f);
        }
        *reinterpret_cast<uint4*>(x1b + (size_t)n * 64 + lane * 8) =
            *reinterpret_cast<const uint4*>(o);
    }
}

// ---------------- layer-2 attention logits ----------------

__global__ __launch_bounds__(256) void att2_k(const u8* __restrict__ h2f,
                                              const float* __restrict__ a2s, const float* __restrict__ a2d,
                                              float* __restrict__ as2, float* __restrict__ ad2, int Nn) {
    int t = blockIdx.x * 256 + threadIdx.x;
    if (t >= Nn * 8) return;
    int n = t >> 3, h = t & 7;
    const u8* hr = h2f + (size_t)n * 320 + h * 40;
    float s1 = 0.f, s2 = 0.f;
#pragma unroll
    for (int b = 0; b < 5; b++) {
        uint2 raw = *reinterpret_cast<const uint2*>(hr + b * 8);
        float h8[8];
        dec8(raw, h8);
#pragma unroll
        for (int j = 0; j < 8; j++) {
            int c = h * 40 + b * 8 + j;
            s1 = fmaf(h8[j], a2s[c], s1);
            s2 = fmaf(h8[j], a2d[c], s2);
        }
    }
    as2[t] = s1;
    ad2[t] = s2;
}

// ---------------- layer-2 aggregation + head-mean + bias + log_softmax ----------------

__global__ __launch_bounds__(256) void agg2_k(const u8* __restrict__ h2f,
                                              const float* __restrict__ as2, const float* __restrict__ ad2,
                                              const int* __restrict__ srcs, const int* __restrict__ rowstart,
                                              const float* __restrict__ b2, float* __restrict__ out, int Nn) {
    __shared__ float smem[4][320];
    int wave = threadIdx.x >> 6, lane = threadIdx.x & 63;
    int n = blockIdx.x * 4 + wave;
    bool active = (n < Nn);
    bool ld = active && (lane < 40);
    const int hl = lane / 5;
    float adl = ld ? ad2[n * 8 + hl] : 0.f;
    float acc[8] = {0, 0, 0, 0, 0, 0, 0, 0};
    float dsum = 0.f;
    if (ld) {
        const size_t loff = (size_t)lane * 8;
        int beg = rowstart[n], end = rowstart[n + 1];
        int i = beg;
        for (; i + 8 <= end; i += 8) {
            int s[8];
#pragma unroll
            for (int u = 0; u < 8; u++) s[u] = srcs[i + u];
            uint2 rw[8];
#pragma unroll
            for (int u = 0; u < 8; u++) rw[u] = *reinterpret_cast<const uint2*>(h2f + (size_t)s[u] * 320 + loff);
            float eg[8];
#pragma unroll
            for (int u = 0; u < 8; u++) eg[u] = as2[s[u] * 8 + hl];
            float p[8];
#pragma unroll
            for (int u = 0; u < 8; u++) { p[u] = lrelu_exp(eg[u] + adl); dsum += p[u]; }
#pragma unroll
            for (int u = 0; u < 8; u++) {
                float hv[8];
                dec8(rw[u], hv);
#pragma unroll
                for (int j = 0; j < 8; j++) acc[j] = fmaf(p[u], hv[j], acc[j]);
            }
        }
        for (; i + 4 <= end; i += 4) {
            int s[4];
#pragma unroll
            for (int u = 0; u < 4; u++) s[u] = srcs[i + u];
            uint2 rw[4];
#pragma unroll
            for (int u = 0; u < 4; u++) rw[u] = *reinterpret_cast<const uint2*>(h2f + (size_t)s[u] * 320 + loff);
#pragma unroll
            for (int u = 0; u < 4; u++) {
                float p = lrelu_exp(as2[s[u] * 8 + hl] + adl);
                dsum += p;
                float hv[8];
                dec8(rw[u], hv);
#pragma unroll
                for (int j = 0; j < 8; j++) acc[j] = fmaf(p, hv[j], acc[j]);
            }
        }
        for (; i < end; i++) {
            int s = srcs[i];
            uint2 raw = *reinterpret_cast<const uint2*>(h2f + (size_t)s * 320 + loff);
            float p = lrelu_exp(as2[s * 8 + hl] + adl);
            dsum += p;
            float hv[8];
            dec8(raw, hv);
#pragma unroll
            for (int j = 0; j < 8; j++) acc[j] = fmaf(p, hv[j], acc[j]);
        }
        float inv = 1.f / (dsum + 1e-16f);
#pragma unroll
        for (int j = 0; j < 8; j++) smem[wave][lane * 8 + j] = acc[j] * inv;
    }
    __syncthreads();
    if (active) {
        float v;
        if (lane < 40) {
            float ssum = 0.f;
#pragma unroll
            for (int h = 0; h < 8; h++) ssum += smem[wave][h * 40 + lane];
            v = ssum * 0.125f + b2[lane];
        } else {
            v = -INFINITY;
        }
        float m = v;
        for (int off = 32; off > 0; off >>= 1) m = fmaxf(m, __shfl_xor(m, off, 64));
        float ex = (lane < 40) ? __expf(v - m) : 0.f;
        float se = ex;
        for (int off = 32; off > 0; off >>= 1) se += __shfl_xor(se, off, 64);
        if (lane < 40) out[(size_t)n * 40 + lane] = v - m - __logf(se);
    }
}

// ---------------- launch ----------------

extern "C" void kernel_launch(void* const* d_in, const int* in_sizes, int n_in,
                              void* d_out, int out_size, void* d_ws, size_t ws_size,
                              hipStream_t stream) {
    const float* x   = (const float*)d_in[0];
    const int*   ei  = (const int*)d_in[1];
    const float* W0  = (const float*)d_in[3];
    const float* a0s = (const float*)d_in[4];
    const float* a0d = (const float*)d_in[5];
    const float* b0  = (const float*)d_in[6];
    const float* W2  = (const float*)d_in[7];
    const float* a2s = (const float*)d_in[8];
    const float* a2d = (const float*)d_in[9];
    const float* b2  = (const float*)d_in[10];
    float* out = (float*)d_out;

    const int Nn = in_sizes[0] / 256;   // 50000
    const int E  = in_sizes[1] / 2;     // 800000
    const int ET = E + Nn;

    size_t off = 0;
    auto carve = [&](size_t bytes) -> void* {
        void* p = (char*)d_ws + off;
        off += (bytes + 255) & ~(size_t)255;
        return p;
    };
    u16*   xb       = (u16*)carve((size_t)Nn * 256 * 2);  // 25.6 MB bf16
    u8*    h1f      = (u8*)carve((size_t)Nn * 512);       // 25.6 MB fp8
    u16*   x1b      = (u16*)carve((size_t)Nn * 64 * 2);
    u8*    h2f      = (u8*)carve((size_t)Nn * 320);       // 16 MB fp8
    float* as1      = (float*)carve((size_t)Nn * 8 * 4);
    float* ad1      = (float*)carve((size_t)Nn * 8 * 4);
    float* as2      = (float*)carve((size_t)Nn * 8 * 4);
    float* ad2      = (float*)carve((size_t)Nn * 8 * 4);
    int*   deg      = (int*)carve((size_t)Nn * 4);
    int*   cursor   = (int*)carve((size_t)Nn * 4);
    int*   rowstart = (int*)carve((size_t)(Nn + 1) * 4);
    int*   srcs     = (int*)carve((size_t)ET * 4);

    hipMemsetAsync(deg, 0, (size_t)Nn * 4, stream);
    hipMemsetAsync(cursor, 0, (size_t)Nn * 4, stream);

    hist_k<<<(ET + 255) / 256, 256, 0, stream>>>(ei, deg, E, Nn);
    scan_k<<<1, 1024, 0, stream>>>(deg, rowstart, Nn, ET);
    scatter_k<<<(ET + 255) / 256, 256, 0, stream>>>(ei, rowstart, cursor, srcs, E, Nn);

    cast_k<<<(Nn * 256 / 4 + 255) / 256, 256, 0, stream>>>(x, xb, Nn * 256);

    // layer 1: GEMM + fused logits (plain stores), fp8 h1
    gemm_mfma<<<dim3((Nn + 127) / 128, 4), 256, 0, stream>>>(
        xb, W0, h1f, Nn, 512, 256, a0s, a0d, as1, ad1);
    agg1_k<<<(Nn + 3) / 4, 256, 0, stream>>>(h1f, as1, ad1, srcs, rowstart, b0, x1b, Nn);

    // layer 2: GEMM, fp8 h2
    gemm_mfma<<<dim3((Nn + 127) / 128, 3), 256, 0, stream>>>(
        x1b, W2, h2f, Nn, 320, 64, nullptr, nullptr, nullptr, nullptr);
    att2_k<<<(Nn * 8 + 255) / 256, 256, 0, stream>>>(h2f, a2s, a2d, as2, ad2, Nn);
    agg2_k<<<(Nn + 3) / 4, 256, 0, stream>>>(h2f, as2, ad2, srcs, rowstart, b2, out, Nn);
}

// Round 7
// 417.454 us; speedup vs baseline: 2.6005x; 1.1743x over previous
//
#include <hip/hip_runtime.h>
#include <hip/hip_bf16.h>
#include <math.h>

// GATNet round 7: single-block scan (93us on one CU, 0.04% of anything)
// replaced by a 3-phase grid-wide scan (scanA: per-block inclusive scan,
// scanB: one-wave scan of <=64 block sums, scanC: combine). Everything
// else unchanged from round 6.

#define NEG_SLOPE 0.2f

typedef short v8s __attribute__((ext_vector_type(8)));
typedef float v4f __attribute__((ext_vector_type(4)));
typedef float v2f __attribute__((ext_vector_type(2)));
typedef unsigned short u16;
typedef unsigned int u32;
typedef unsigned char u8;

__device__ __forceinline__ u16 f2bf(float f) {
    union { float f; u32 u; } v; v.f = f;
    u32 r = v.u + 0x7fffu + ((v.u >> 16) & 1u);
    return (u16)(r >> 16);
}
__device__ __forceinline__ float lrelu_exp(float e) {
    e = (e > 0.f) ? e : NEG_SLOPE * e;
    return __expf(e);
}
__device__ __forceinline__ void dec8(uint2 r, float* h) {
    v2f a = __builtin_amdgcn_cvt_pk_f32_fp8(r.x, false);
    v2f b = __builtin_amdgcn_cvt_pk_f32_fp8(r.x, true);
    v2f c = __builtin_amdgcn_cvt_pk_f32_fp8(r.y, false);
    v2f d = __builtin_amdgcn_cvt_pk_f32_fp8(r.y, true);
    h[0] = a.x; h[1] = a.y; h[2] = b.x; h[3] = b.y;
    h[4] = c.x; h[5] = c.y; h[6] = d.x; h[7] = d.y;
}
__device__ __forceinline__ u8 enc8(float v) {
    u32 p = __builtin_amdgcn_cvt_pk_fp8_f32(v, v, 0u, false);
    return (u8)(p & 0xffu);
}

// ---------------- CSR build ----------------

__global__ __launch_bounds__(256) void hist_k(const int* __restrict__ ei, int* __restrict__ deg,
                                              int E, int Nn) {
    int e = blockIdx.x * 256 + threadIdx.x;
    int ET = E + Nn;
    if (e >= ET) return;
    int d = (e < E) ? ei[E + e] : (e - E);
    atomicAdd(&deg[d], 1);
}

// phase A: per-block (1024 elems) inclusive scan -> incl[], block total -> bsum[b]
__global__ __launch_bounds__(1024) void scanA_k(const int* __restrict__ deg, int* __restrict__ incl,
                                                int* __restrict__ bsum, int n) {
    __shared__ int wsum[16];
    int t = threadIdx.x;
    int i = blockIdx.x * 1024 + t;
    int v = (i < n) ? deg[i] : 0;
    int lane = t & 63, wid = t >> 6;
    int sv = v;
    for (int off = 1; off < 64; off <<= 1) {
        int u = __shfl_up(sv, off, 64);
        if (lane >= off) sv += u;
    }
    if (lane == 63) wsum[wid] = sv;
    __syncthreads();
    if (t < 16) {
        int w = wsum[t];
        for (int off = 1; off < 16; off <<= 1) {
            int u = __shfl_up(w, off, 64);
            if (t >= off) w += u;
        }
        wsum[t] = w;
    }
    __syncthreads();
    int pre = (wid > 0) ? wsum[wid - 1] : 0;
    int inc = pre + sv;
    if (i < n) incl[i] = inc;
    if (t == 1023) bsum[blockIdx.x] = inc;
}

// phase B: one wave scans B (<=64) block sums -> exclusive boff[], total -> boff[B]
__global__ __launch_bounds__(64) void scanB_k(const int* __restrict__ bsum, int* __restrict__ boff, int B) {
    int t = threadIdx.x;
    int v = (t < B) ? bsum[t] : 0;
    int sv = v;
    for (int off = 1; off < 64; off <<= 1) {
        int u = __shfl_up(sv, off, 64);
        if (t >= off) sv += u;
    }
    if (t < B) boff[t] = sv - v;
    if (t == 63) boff[B] = sv;
}

// phase C: exclusive rowstart[i] = boff[block] + incl[i] - deg[i]; rowstart[n]=total
__global__ __launch_bounds__(256) void scanC_k(const int* __restrict__ incl, const int* __restrict__ deg,
                                               const int* __restrict__ boff, int* __restrict__ rowstart,
                                               int n, int B) {
    int i = blockIdx.x * 256 + threadIdx.x;
    if (i < n) rowstart[i] = boff[i >> 10] + incl[i] - deg[i];
    if (i == 0) rowstart[n] = boff[B];
}

__global__ __launch_bounds__(256) void scatter_k(const int* __restrict__ ei,
                                                 const int* __restrict__ rowstart,
                                                 int* __restrict__ cursor,
                                                 int* __restrict__ srcs, int E, int Nn) {
    int e = blockIdx.x * 256 + threadIdx.x;
    int ET = E + Nn;
    if (e >= ET) return;
    int s, d;
    if (e < E) { s = ei[e]; d = ei[E + e]; }
    else       { s = e - E; d = e - E; }
    int pos = atomicAdd(&cursor[d], 1);
    srcs[rowstart[d] + pos] = s;
}

// ---------------- fp32 -> bf16 cast ----------------

__global__ __launch_bounds__(256) void cast_k(const float* __restrict__ in, u16* __restrict__ out, int n) {
    int i = (blockIdx.x * 256 + threadIdx.x) * 4;
    if (i + 3 < n) {
        float4 v = *reinterpret_cast<const float4*>(in + i);
        ushort4 o;
        o.x = f2bf(v.x); o.y = f2bf(v.y); o.z = f2bf(v.z); o.w = f2bf(v.w);
        *reinterpret_cast<ushort4*>(out + i) = o;
    } else {
        for (int j = i; j < n; j++) out[j] = f2bf(in[j]);
    }
}

// ---------------- bf16 MFMA GEMM -> fp8 C (coalesced LDS-repacked store) ----------------

__global__ __launch_bounds__(256) void gemm_mfma(const u16* __restrict__ Ab,
                                                 const float* __restrict__ Bf,
                                                 u8* __restrict__ Cf, int M, int Nc, int K,
                                                 const float* __restrict__ avs_vec,
                                                 const float* __restrict__ avd_vec,
                                                 float* as_out, float* ad_out) {
    __shared__ __align__(16) u8 lds[20480];
    u16 (*As)[40] = reinterpret_cast<u16(*)[40]>(lds);
    u16 (*Bs)[40] = reinterpret_cast<u16(*)[40]>(lds + 10240);
    const int t = threadIdx.x;
    const int m0 = blockIdx.x * 128;
    const int n0 = blockIdx.y * 128;
    const int w = t >> 6, lane = t & 63;
    const int wr = (w >> 1) * 64, wc = (w & 1) * 64;
    const int q = lane >> 4, l16 = lane & 15;
    const int r0 = t >> 2;
    const int c8 = (t & 3) * 8;

    v4f acc[4][4];
#pragma unroll
    for (int i = 0; i < 4; i++)
#pragma unroll
        for (int j = 0; j < 4; j++) acc[i][j] = (v4f){0.f, 0.f, 0.f, 0.f};

    for (int kt = 0; kt < K; kt += 32) {
#pragma unroll
        for (int p = 0; p < 2; p++) {
            int r = r0 + p * 64;
            int gm = m0 + r;
            uint4 va = make_uint4(0u, 0u, 0u, 0u);
            if (gm < M) va = *reinterpret_cast<const uint4*>(Ab + (size_t)gm * K + kt + c8);
            *reinterpret_cast<uint4*>(&As[r][c8]) = va;
            int gn = n0 + r;
            u16 b8[8] = {0, 0, 0, 0, 0, 0, 0, 0};
            if (gn < Nc) {
                float4 w0 = *reinterpret_cast<const float4*>(Bf + (size_t)gn * K + kt + c8);
                float4 w1 = *reinterpret_cast<const float4*>(Bf + (size_t)gn * K + kt + c8 + 4);
                b8[0] = f2bf(w0.x); b8[1] = f2bf(w0.y); b8[2] = f2bf(w0.z); b8[3] = f2bf(w0.w);
                b8[4] = f2bf(w1.x); b8[5] = f2bf(w1.y); b8[6] = f2bf(w1.z); b8[7] = f2bf(w1.w);
            }
            *reinterpret_cast<uint4*>(&Bs[r][c8]) = *reinterpret_cast<const uint4*>(b8);
        }
        __syncthreads();
        v8s af[4], bf[4];
#pragma unroll
        for (int i = 0; i < 4; i++) af[i] = *reinterpret_cast<const v8s*>(&As[wr + i * 16 + l16][q * 8]);
#pragma unroll
        for (int j = 0; j < 4; j++) bf[j] = *reinterpret_cast<const v8s*>(&Bs[wc + j * 16 + l16][q * 8]);
#pragma unroll
        for (int i = 0; i < 4; i++)
#pragma unroll
            for (int j = 0; j < 4; j++)
                acc[i][j] = __builtin_amdgcn_mfma_f32_16x16x32_bf16(af[i], bf[j], acc[i][j], 0, 0, 0);
        __syncthreads();
    }

    const bool do_att = (as_out != nullptr);
    float avs[4], avd[4];
    if (do_att) {
#pragma unroll
        for (int j = 0; j < 4; j++) {
            int gn = n0 + wc + j * 16 + l16;
            avs[j] = (gn < Nc) ? avs_vec[gn] : 0.f;
            avd[j] = (gn < Nc) ? avd_vec[gn] : 0.f;
        }
    }
    const int head = (n0 + wc) >> 6;

    u8* Cs = lds;
#pragma unroll
    for (int i = 0; i < 4; i++) {
#pragma unroll
        for (int r = 0; r < 4; r++) {
            int row = wr + i * 16 + q * 4 + r;
#pragma unroll
            for (int j = 0; j < 4; j++)
                Cs[row * 144 + wc + j * 16 + l16] = enc8(acc[i][j][r]);
            if (do_att) {
                int gm = m0 + row;
                float ps = 0.f, pd = 0.f;
#pragma unroll
                for (int j = 0; j < 4; j++) {
                    float v = acc[i][j][r];
                    ps = fmaf(v, avs[j], ps);
                    pd = fmaf(v, avd[j], pd);
                }
#pragma unroll
                for (int m = 1; m < 16; m <<= 1) {
                    ps += __shfl_xor(ps, m, 64);
                    pd += __shfl_xor(pd, m, 64);
                }
                if (l16 == 0 && gm < M) {
                    as_out[gm * 8 + head] = ps;   // complete dot: no atomics
                    ad_out[gm * 8 + head] = pd;
                }
            }
        }
    }
    __syncthreads();
#pragma unroll
    for (int it = 0; it < 4; it++) {
        int idx = it * 256 + t;
        int row = idx >> 3, ch = idx & 7;
        int gm = m0 + row, gn = n0 + ch * 16;
        if (gm < M && gn < Nc)
            *reinterpret_cast<uint4*>(Cf + (size_t)gm * Nc + gn) =
                *reinterpret_cast<const uint4*>(&Cs[row * 144 + ch * 16]);
    }
}

// ---------------- layer-1 aggregation: wave/dst, 8-deep fp8 gather, bf16 x1 out ----------------

__global__ __launch_bounds__(256) void agg1_k(const u8* __restrict__ h1f,
                                              const float* __restrict__ as1, const float* __restrict__ ad1,
                                              const int* __restrict__ srcs, const int* __restrict__ rowstart,
                                              const float* __restrict__ b0, u16* __restrict__ x1b, int Nn) {
    int wave = threadIdx.x >> 6, lane = threadIdx.x & 63;
    int n = blockIdx.x * 4 + wave;
    if (n >= Nn) return;
    const int hl = lane >> 3;
    const float adl = ad1[n * 8 + hl];
    const size_t loff = (size_t)lane * 8;
    float acc[8] = {0, 0, 0, 0, 0, 0, 0, 0};
    float dsum = 0.f;
    int beg = rowstart[n], end = rowstart[n + 1];
    int i = beg;
    for (; i + 8 <= end; i += 8) {
        int s[8];
#pragma unroll
        for (int u = 0; u < 8; u++) s[u] = srcs[i + u];
        uint2 rw[8];
#pragma unroll
        for (int u = 0; u < 8; u++) rw[u] = *reinterpret_cast<const uint2*>(h1f + (size_t)s[u] * 512 + loff);
        float eg[8];
#pragma unroll
        for (int u = 0; u < 8; u++) eg[u] = as1[s[u] * 8 + hl];
        float p[8];
#pragma unroll
        for (int u = 0; u < 8; u++) { p[u] = lrelu_exp(eg[u] + adl); dsum += p[u]; }
#pragma unroll
        for (int u = 0; u < 8; u++) {
            float hv[8];
            dec8(rw[u], hv);
#pragma unroll
            for (int j = 0; j < 8; j++) acc[j] = fmaf(p[u], hv[j], acc[j]);
        }
    }
    for (; i + 4 <= end; i += 4) {
        int s[4];
#pragma unroll
        for (int u = 0; u < 4; u++) s[u] = srcs[i + u];
        uint2 rw[4];
#pragma unroll
        for (int u = 0; u < 4; u++) rw[u] = *reinterpret_cast<const uint2*>(h1f + (size_t)s[u] * 512 + loff);
#pragma unroll
        for (int u = 0; u < 4; u++) {
            float p = lrelu_exp(as1[s[u] * 8 + hl] + adl);
            dsum += p;
            float hv[8];
            dec8(rw[u], hv);
#pragma unroll
            for (int j = 0; j < 8; j++) acc[j] = fmaf(p, hv[j], acc[j]);
        }
    }
    for (; i < end; i++) {
        int s = srcs[i];
        uint2 raw = *reinterpret_cast<const uint2*>(h1f + (size_t)s * 512 + loff);
        float p = lrelu_exp(as1[s * 8 + hl] + adl);
        dsum += p;
        float hv[8];
        dec8(raw, hv);
#pragma unroll
        for (int j = 0; j < 8; j++) acc[j] = fmaf(p, hv[j], acc[j]);
    }
    float inv = 1.f / (dsum + 1e-16f);
    float r[8];
#pragma unroll
    for (int j = 0; j < 8; j++) r[j] = acc[j] * inv;
#pragma unroll
    for (int j = 0; j < 8; j++) {
        r[j] += __shfl_xor(r[j], 8, 64);
        r[j] += __shfl_xor(r[j], 16, 64);
        r[j] += __shfl_xor(r[j], 32, 64);
    }
    if (lane < 8) {
        u16 o[8];
#pragma unroll
        for (int j = 0; j < 8; j++) {
            float v = r[j] * 0.125f + b0[lane * 8 + j];
            o[j] = f2bf((v > 0.f) ? v : 0.f);
        }
        *reinterpret_cast<uint4*>(x1b + (size_t)n * 64 + lane * 8) =
            *reinterpret_cast<const uint4*>(o);
    }
}

// ---------------- layer-2 attention logits ----------------

__global__ __launch_bounds__(256) void att2_k(const u8* __restrict__ h2f,
                                              const float* __restrict__ a2s, const float* __restrict__ a2d,
                                              float* __restrict__ as2, float* __restrict__ ad2, int Nn) {
    int t = blockIdx.x * 256 + threadIdx.x;
    if (t >= Nn * 8) return;
    int n = t >> 3, h = t & 7;
    const u8* hr = h2f + (size_t)n * 320 + h * 40;
    float s1 = 0.f, s2 = 0.f;
#pragma unroll
    for (int b = 0; b < 5; b++) {
        uint2 raw = *reinterpret_cast<const uint2*>(hr + b * 8);
        float h8[8];
        dec8(raw, h8);
#pragma unroll
        for (int j = 0; j < 8; j++) {
            int c = h * 40 + b * 8 + j;
            s1 = fmaf(h8[j], a2s[c], s1);
            s2 = fmaf(h8[j], a2d[c], s2);
        }
    }
    as2[t] = s1;
    ad2[t] = s2;
}

// ---------------- layer-2 aggregation + head-mean + bias + log_softmax ----------------

__global__ __launch_bounds__(256) void agg2_k(const u8* __restrict__ h2f,
                                              const float* __restrict__ as2, const float* __restrict__ ad2,
                                              const int* __restrict__ srcs, const int* __restrict__ rowstart,
                                              const float* __restrict__ b2, float* __restrict__ out, int Nn) {
    __shared__ float smem[4][320];
    int wave = threadIdx.x >> 6, lane = threadIdx.x & 63;
    int n = blockIdx.x * 4 + wave;
    bool active = (n < Nn);
    bool ld = active && (lane < 40);
    const int hl = lane / 5;
    float adl = ld ? ad2[n * 8 + hl] : 0.f;
    float acc[8] = {0, 0, 0, 0, 0, 0, 0, 0};
    float dsum = 0.f;
    if (ld) {
        const size_t loff = (size_t)lane * 8;
        int beg = rowstart[n], end = rowstart[n + 1];
        int i = beg;
        for (; i + 8 <= end; i += 8) {
            int s[8];
#pragma unroll
            for (int u = 0; u < 8; u++) s[u] = srcs[i + u];
            uint2 rw[8];
#pragma unroll
            for (int u = 0; u < 8; u++) rw[u] = *reinterpret_cast<const uint2*>(h2f + (size_t)s[u] * 320 + loff);
            float eg[8];
#pragma unroll
            for (int u = 0; u < 8; u++) eg[u] = as2[s[u] * 8 + hl];
            float p[8];
#pragma unroll
            for (int u = 0; u < 8; u++) { p[u] = lrelu_exp(eg[u] + adl); dsum += p[u]; }
#pragma unroll
            for (int u = 0; u < 8; u++) {
                float hv[8];
                dec8(rw[u], hv);
#pragma unroll
                for (int j = 0; j < 8; j++) acc[j] = fmaf(p[u], hv[j], acc[j]);
            }
        }
        for (; i + 4 <= end; i += 4) {
            int s[4];
#pragma unroll
            for (int u = 0; u < 4; u++) s[u] = srcs[i + u];
            uint2 rw[4];
#pragma unroll
            for (int u = 0; u < 4; u++) rw[u] = *reinterpret_cast<const uint2*>(h2f + (size_t)s[u] * 320 + loff);
#pragma unroll
            for (int u = 0; u < 4; u++) {
                float p = lrelu_exp(as2[s[u] * 8 + hl] + adl);
                dsum += p;
                float hv[8];
                dec8(rw[u], hv);
#pragma unroll
                for (int j = 0; j < 8; j++) acc[j] = fmaf(p, hv[j], acc[j]);
            }
        }
        for (; i < end; i++) {
            int s = srcs[i];
            uint2 raw = *reinterpret_cast<const uint2*>(h2f + (size_t)s * 320 + loff);
            float p = lrelu_exp(as2[s * 8 + hl] + adl);
            dsum += p;
            float hv[8];
            dec8(raw, hv);
#pragma unroll
            for (int j = 0; j < 8; j++) acc[j] = fmaf(p, hv[j], acc[j]);
        }
        float inv = 1.f / (dsum + 1e-16f);
#pragma unroll
        for (int j = 0; j < 8; j++) smem[wave][lane * 8 + j] = acc[j] * inv;
    }
    __syncthreads();
    if (active) {
        float v;
        if (lane < 40) {
            float ssum = 0.f;
#pragma unroll
            for (int h = 0; h < 8; h++) ssum += smem[wave][h * 40 + lane];
            v = ssum * 0.125f + b2[lane];
        } else {
            v = -INFINITY;
        }
        float m = v;
        for (int off = 32; off > 0; off >>= 1) m = fmaxf(m, __shfl_xor(m, off, 64));
        float ex = (lane < 40) ? __expf(v - m) : 0.f;
        float se = ex;
        for (int off = 32; off > 0; off >>= 1) se += __shfl_xor(se, off, 64);
        if (lane < 40) out[(size_t)n * 40 + lane] = v - m - __logf(se);
    }
}

// ---------------- launch ----------------

extern "C" void kernel_launch(void* const* d_in, const int* in_sizes, int n_in,
                              void* d_out, int out_size, void* d_ws, size_t ws_size,
                              hipStream_t stream) {
    const float* x   = (const float*)d_in[0];
    const int*   ei  = (const int*)d_in[1];
    const float* W0  = (const float*)d_in[3];
    const float* a0s = (const float*)d_in[4];
    const float* a0d = (const float*)d_in[5];
    const float* b0  = (const float*)d_in[6];
    const float* W2  = (const float*)d_in[7];
    const float* a2s = (const float*)d_in[8];
    const float* a2d = (const float*)d_in[9];
    const float* b2  = (const float*)d_in[10];
    float* out = (float*)d_out;

    const int Nn = in_sizes[0] / 256;   // 50000
    const int E  = in_sizes[1] / 2;     // 800000
    const int ET = E + Nn;
    const int NB = (Nn + 1023) / 1024;  // scan blocks (<=64)

    size_t off = 0;
    auto carve = [&](size_t bytes) -> void* {
        void* p = (char*)d_ws + off;
        off += (bytes + 255) & ~(size_t)255;
        return p;
    };
    u16*   xb       = (u16*)carve((size_t)Nn * 256 * 2);  // 25.6 MB bf16
    u8*    h1f      = (u8*)carve((size_t)Nn * 512);       // 25.6 MB fp8
    u16*   x1b      = (u16*)carve((size_t)Nn * 64 * 2);
    u8*    h2f      = (u8*)carve((size_t)Nn * 320);       // 16 MB fp8
    float* as1      = (float*)carve((size_t)Nn * 8 * 4);
    float* ad1      = (float*)carve((size_t)Nn * 8 * 4);
    float* as2      = (float*)carve((size_t)Nn * 8 * 4);
    float* ad2      = (float*)carve((size_t)Nn * 8 * 4);
    int*   deg      = (int*)carve((size_t)Nn * 4);
    int*   cursor   = (int*)carve((size_t)Nn * 4);
    int*   rowstart = (int*)carve((size_t)(Nn + 1) * 4);
    int*   srcs     = (int*)carve((size_t)ET * 4);
    int*   incl     = (int*)carve((size_t)Nn * 4);
    int*   bsum     = (int*)carve(64 * 4);
    int*   boff     = (int*)carve(65 * 4);

    hipMemsetAsync(deg, 0, (size_t)Nn * 4, stream);
    hipMemsetAsync(cursor, 0, (size_t)Nn * 4, stream);

    hist_k<<<(ET + 255) / 256, 256, 0, stream>>>(ei, deg, E, Nn);
    scanA_k<<<NB, 1024, 0, stream>>>(deg, incl, bsum, Nn);
    scanB_k<<<1, 64, 0, stream>>>(bsum, boff, NB);
    scanC_k<<<(Nn + 255) / 256, 256, 0, stream>>>(incl, deg, boff, rowstart, Nn, NB);
    scatter_k<<<(ET + 255) / 256, 256, 0, stream>>>(ei, rowstart, cursor, srcs, E, Nn);

    cast_k<<<(Nn * 256 / 4 + 255) / 256, 256, 0, stream>>>(x, xb, Nn * 256);

    // layer 1: GEMM + fused logits (plain stores), fp8 h1
    gemm_mfma<<<dim3((Nn + 127) / 128, 4), 256, 0, stream>>>(
        xb, W0, h1f, Nn, 512, 256, a0s, a0d, as1, ad1);
    agg1_k<<<(Nn + 3) / 4, 256, 0, stream>>>(h1f, as1, ad1, srcs, rowstart, b0, x1b, Nn);

    // layer 2: GEMM, fp8 h2
    gemm_mfma<<<dim3((Nn + 127) / 128, 3), 256, 0, stream>>>(
        x1b, W2, h2f, Nn, 320, 64, nullptr, nullptr, nullptr, nullptr);
    att2_k<<<(Nn * 8 + 255) / 256, 256, 0, stream>>>(h2f, a2s, a2d, as2, ad2, Nn);
    agg2_k<<<(Nn + 3) / 4, 256, 0, stream>>>(h2f, as2, ad2, srcs, rowstart, b2, out, Nn);
}

// Round 8
// 404.296 us; speedup vs baseline: 2.6851x; 1.0325x over previous
//
#include <hip/hip_runtime.h>
#include <hip/hip_bf16.h>
#include <math.h>

// GATNet round 8: GEMM restructured for occupancy. Round-7 counters showed
// 140 unified regs (76 VGPR + 64 AGPR) -> 2 waves/SIMD (25% occ), all pipes
// <25% busy. New shape: 128x64 block tile, wave = 32 rows x 64 cols ->
// acc 32 AGPR, __launch_bounds__(256,4) -> 4 waves/SIMD. BK=64 (half the
// barriers), B pre-cast to bf16 (no staging converts). Fused att1 logits:
// block's 64-col slab == one head -> plain per-row store.

#define NEG_SLOPE 0.2f

typedef short v8s __attribute__((ext_vector_type(8)));
typedef float v4f __attribute__((ext_vector_type(4)));
typedef float v2f __attribute__((ext_vector_type(2)));
typedef unsigned short u16;
typedef unsigned int u32;
typedef unsigned char u8;

__device__ __forceinline__ u16 f2bf(float f) {
    union { float f; u32 u; } v; v.f = f;
    u32 r = v.u + 0x7fffu + ((v.u >> 16) & 1u);
    return (u16)(r >> 16);
}
__device__ __forceinline__ float lrelu_exp(float e) {
    e = (e > 0.f) ? e : NEG_SLOPE * e;
    return __expf(e);
}
__device__ __forceinline__ void dec8(uint2 r, float* h) {
    v2f a = __builtin_amdgcn_cvt_pk_f32_fp8(r.x, false);
    v2f b = __builtin_amdgcn_cvt_pk_f32_fp8(r.x, true);
    v2f c = __builtin_amdgcn_cvt_pk_f32_fp8(r.y, false);
    v2f d = __builtin_amdgcn_cvt_pk_f32_fp8(r.y, true);
    h[0] = a.x; h[1] = a.y; h[2] = b.x; h[3] = b.y;
    h[4] = c.x; h[5] = c.y; h[6] = d.x; h[7] = d.y;
}
__device__ __forceinline__ u8 enc8(float v) {
    u32 p = __builtin_amdgcn_cvt_pk_fp8_f32(v, v, 0u, false);
    return (u8)(p & 0xffu);
}

// ---------------- CSR build ----------------

__global__ __launch_bounds__(256) void hist_k(const int* __restrict__ ei, int* __restrict__ deg,
                                              int E, int Nn) {
    int e = blockIdx.x * 256 + threadIdx.x;
    int ET = E + Nn;
    if (e >= ET) return;
    int d = (e < E) ? ei[E + e] : (e - E);
    atomicAdd(&deg[d], 1);
}

__global__ __launch_bounds__(1024) void scanA_k(const int* __restrict__ deg, int* __restrict__ incl,
                                                int* __restrict__ bsum, int n) {
    __shared__ int wsum[16];
    int t = threadIdx.x;
    int i = blockIdx.x * 1024 + t;
    int v = (i < n) ? deg[i] : 0;
    int lane = t & 63, wid = t >> 6;
    int sv = v;
    for (int off = 1; off < 64; off <<= 1) {
        int u = __shfl_up(sv, off, 64);
        if (lane >= off) sv += u;
    }
    if (lane == 63) wsum[wid] = sv;
    __syncthreads();
    if (t < 16) {
        int w = wsum[t];
        for (int off = 1; off < 16; off <<= 1) {
            int u = __shfl_up(w, off, 64);
            if (t >= off) w += u;
        }
        wsum[t] = w;
    }
    __syncthreads();
    int pre = (wid > 0) ? wsum[wid - 1] : 0;
    int inc = pre + sv;
    if (i < n) incl[i] = inc;
    if (t == 1023) bsum[blockIdx.x] = inc;
}

__global__ __launch_bounds__(64) void scanB_k(const int* __restrict__ bsum, int* __restrict__ boff, int B) {
    int t = threadIdx.x;
    int v = (t < B) ? bsum[t] : 0;
    int sv = v;
    for (int off = 1; off < 64; off <<= 1) {
        int u = __shfl_up(sv, off, 64);
        if (t >= off) sv += u;
    }
    if (t < B) boff[t] = sv - v;
    if (t == 63) boff[B] = sv;
}

__global__ __launch_bounds__(256) void scanC_k(const int* __restrict__ incl, const int* __restrict__ deg,
                                               const int* __restrict__ boff, int* __restrict__ rowstart,
                                               int n, int B) {
    int i = blockIdx.x * 256 + threadIdx.x;
    if (i < n) rowstart[i] = boff[i >> 10] + incl[i] - deg[i];
    if (i == 0) rowstart[n] = boff[B];
}

__global__ __launch_bounds__(256) void scatter_k(const int* __restrict__ ei,
                                                 const int* __restrict__ rowstart,
                                                 int* __restrict__ cursor,
                                                 int* __restrict__ srcs, int E, int Nn) {
    int e = blockIdx.x * 256 + threadIdx.x;
    int ET = E + Nn;
    if (e >= ET) return;
    int s, d;
    if (e < E) { s = ei[e]; d = ei[E + e]; }
    else       { s = e - E; d = e - E; }
    int pos = atomicAdd(&cursor[d], 1);
    srcs[rowstart[d] + pos] = s;
}

// ---------------- fp32 -> bf16 cast ----------------

__global__ __launch_bounds__(256) void cast_k(const float* __restrict__ in, u16* __restrict__ out, int n) {
    int i = (blockIdx.x * 256 + threadIdx.x) * 4;
    if (i + 3 < n) {
        float4 v = *reinterpret_cast<const float4*>(in + i);
        ushort4 o;
        o.x = f2bf(v.x); o.y = f2bf(v.y); o.z = f2bf(v.z); o.w = f2bf(v.w);
        *reinterpret_cast<ushort4*>(out + i) = o;
    } else {
        for (int j = i; j < n; j++) out[j] = f2bf(in[j]);
    }
}

// ---------------- bf16 MFMA GEMM -> fp8 C ----------------
// 128x64 block tile, BK=64, 4 waves; wave w computes rows w*32..w*32+31 x
// all 64 cols (acc 2x4 v4f = 32 AGPR). Both A and B are bf16. Fused layer-1
// logits: block's 64 cols == one head -> complete per-row dot, plain store.

__global__ __launch_bounds__(256, 4) void gemm_mfma(const u16* __restrict__ Ab,
                                                    const u16* __restrict__ Bb,
                                                    u8* __restrict__ Cf, int M, int Nc, int K,
                                                    const float* __restrict__ avs_vec,
                                                    const float* __restrict__ avd_vec,
                                                    float* as_out, float* ad_out) {
    __shared__ __align__(16) u8 lds[27648];
    u16 (*As)[72] = reinterpret_cast<u16(*)[72]>(lds);           // 128 rows
    u16 (*Bs)[72] = reinterpret_cast<u16(*)[72]>(lds + 18432);   // 64 rows
    const int t = threadIdx.x;
    const int m0 = blockIdx.x * 128;
    const int n0 = blockIdx.y * 64;
    const int w = t >> 6, lane = t & 63;
    const int wr = w * 32;
    const int q = lane >> 4, l16 = lane & 15;

    v4f acc[2][4];
#pragma unroll
    for (int i = 0; i < 2; i++)
#pragma unroll
        for (int j = 0; j < 4; j++) acc[i][j] = (v4f){0.f, 0.f, 0.f, 0.f};

    for (int kt = 0; kt < K; kt += 64) {
#pragma unroll
        for (int it = 0; it < 4; it++) {
            int c = it * 256 + t;
            int row = c >> 3, col8 = (c & 7) * 8;
            int gm = m0 + row;
            uint4 va = make_uint4(0u, 0u, 0u, 0u);
            if (gm < M) va = *reinterpret_cast<const uint4*>(Ab + (size_t)gm * K + kt + col8);
            *reinterpret_cast<uint4*>(&As[row][col8]) = va;
        }
#pragma unroll
        for (int it = 0; it < 2; it++) {
            int c = it * 256 + t;
            int row = c >> 3, col8 = (c & 7) * 8;
            uint4 vb = *reinterpret_cast<const uint4*>(Bb + (size_t)(n0 + row) * K + kt + col8);
            *reinterpret_cast<uint4*>(&Bs[row][col8]) = vb;
        }
        __syncthreads();
#pragma unroll
        for (int ks = 0; ks < 2; ks++) {
            v8s af[2], bf[4];
#pragma unroll
            for (int i = 0; i < 2; i++)
                af[i] = *reinterpret_cast<const v8s*>(&As[wr + i * 16 + l16][ks * 32 + q * 8]);
#pragma unroll
            for (int j = 0; j < 4; j++)
                bf[j] = *reinterpret_cast<const v8s*>(&Bs[j * 16 + l16][ks * 32 + q * 8]);
#pragma unroll
            for (int i = 0; i < 2; i++)
#pragma unroll
                for (int j = 0; j < 4; j++)
                    acc[i][j] = __builtin_amdgcn_mfma_f32_16x16x32_bf16(af[i], bf[j], acc[i][j], 0, 0, 0);
        }
        __syncthreads();
    }

    const bool do_att = (as_out != nullptr);
    float avs[4], avd[4];
    if (do_att) {
#pragma unroll
        for (int j = 0; j < 4; j++) {
            avs[j] = avs_vec[n0 + j * 16 + l16];
            avd[j] = avd_vec[n0 + j * 16 + l16];
        }
    }
    const int head = n0 >> 6;

    // encode C tile into LDS (row stride 80B), fused logits via plain store
    u8* Cs = lds;
#pragma unroll
    for (int i = 0; i < 2; i++) {
#pragma unroll
        for (int r = 0; r < 4; r++) {
            int row = wr + i * 16 + q * 4 + r;
#pragma unroll
            for (int j = 0; j < 4; j++)
                Cs[row * 80 + j * 16 + l16] = enc8(acc[i][j][r]);
            if (do_att) {
                int gm = m0 + row;
                float ps = 0.f, pd = 0.f;
#pragma unroll
                for (int j = 0; j < 4; j++) {
                    float v = acc[i][j][r];
                    ps = fmaf(v, avs[j], ps);
                    pd = fmaf(v, avd[j], pd);
                }
#pragma unroll
                for (int m = 1; m < 16; m <<= 1) {
                    ps += __shfl_xor(ps, m, 64);
                    pd += __shfl_xor(pd, m, 64);
                }
                if (l16 == 0 && gm < M) {
                    as_out[gm * 8 + head] = ps;
                    ad_out[gm * 8 + head] = pd;
                }
            }
        }
    }
    __syncthreads();
#pragma unroll
    for (int it = 0; it < 2; it++) {
        int idx = it * 256 + t;
        int row = idx >> 2, ch = idx & 3;
        int gm = m0 + row;
        if (gm < M)
            *reinterpret_cast<uint4*>(Cf + (size_t)gm * Nc + n0 + ch * 16) =
                *reinterpret_cast<const uint4*>(&Cs[row * 80 + ch * 16]);
    }
}

// ---------------- layer-1 aggregation: wave/dst, 8-deep fp8 gather, bf16 x1 out ----------------

__global__ __launch_bounds__(256) void agg1_k(const u8* __restrict__ h1f,
                                              const float* __restrict__ as1, const float* __restrict__ ad1,
                                              const int* __restrict__ srcs, const int* __restrict__ rowstart,
                                              const float* __restrict__ b0, u16* __restrict__ x1b, int Nn) {
    int wave = threadIdx.x >> 6, lane = threadIdx.x & 63;
    int n = blockIdx.x * 4 + wave;
    if (n >= Nn) return;
    const int hl = lane >> 3;
    const float adl = ad1[n * 8 + hl];
    const size_t loff = (size_t)lane * 8;
    float acc[8] = {0, 0, 0, 0, 0, 0, 0, 0};
    float dsum = 0.f;
    int beg = rowstart[n], end = rowstart[n + 1];
    int i = beg;
    for (; i + 8 <= end; i += 8) {
        int s[8];
#pragma unroll
        for (int u = 0; u < 8; u++) s[u] = srcs[i + u];
        uint2 rw[8];
#pragma unroll
        for (int u = 0; u < 8; u++) rw[u] = *reinterpret_cast<const uint2*>(h1f + (size_t)s[u] * 512 + loff);
        float eg[8];
#pragma unroll
        for (int u = 0; u < 8; u++) eg[u] = as1[s[u] * 8 + hl];
        float p[8];
#pragma unroll
        for (int u = 0; u < 8; u++) { p[u] = lrelu_exp(eg[u] + adl); dsum += p[u]; }
#pragma unroll
        for (int u = 0; u < 8; u++) {
            float hv[8];
            dec8(rw[u], hv);
#pragma unroll
            for (int j = 0; j < 8; j++) acc[j] = fmaf(p[u], hv[j], acc[j]);
        }
    }
    for (; i + 4 <= end; i += 4) {
        int s[4];
#pragma unroll
        for (int u = 0; u < 4; u++) s[u] = srcs[i + u];
        uint2 rw[4];
#pragma unroll
        for (int u = 0; u < 4; u++) rw[u] = *reinterpret_cast<const uint2*>(h1f + (size_t)s[u] * 512 + loff);
#pragma unroll
        for (int u = 0; u < 4; u++) {
            float p = lrelu_exp(as1[s[u] * 8 + hl] + adl);
            dsum += p;
            float hv[8];
            dec8(rw[u], hv);
#pragma unroll
            for (int j = 0; j < 8; j++) acc[j] = fmaf(p, hv[j], acc[j]);
        }
    }
    for (; i < end; i++) {
        int s = srcs[i];
        uint2 raw = *reinterpret_cast<const uint2*>(h1f + (size_t)s * 512 + loff);
        float p = lrelu_exp(as1[s * 8 + hl] + adl);
        dsum += p;
        float hv[8];
        dec8(raw, hv);
#pragma unroll
        for (int j = 0; j < 8; j++) acc[j] = fmaf(p, hv[j], acc[j]);
    }
    float inv = 1.f / (dsum + 1e-16f);
    float r[8];
#pragma unroll
    for (int j = 0; j < 8; j++) r[j] = acc[j] * inv;
#pragma unroll
    for (int j = 0; j < 8; j++) {
        r[j] += __shfl_xor(r[j], 8, 64);
        r[j] += __shfl_xor(r[j], 16, 64);
        r[j] += __shfl_xor(r[j], 32, 64);
    }
    if (lane < 8) {
        u16 o[8];
#pragma unroll
        for (int j = 0; j < 8; j++) {
            float v = r[j] * 0.125f + b0[lane * 8 + j];
            o[j] = f2bf((v > 0.f) ? v : 0.f);
        }
        *reinterpret_cast<uint4*>(x1b + (size_t)n * 64 + lane * 8) =
            *reinterpret_cast<const uint4*>(o);
    }
}

// ---------------- layer-2 attention logits ----------------

__global__ __launch_bounds__(256) void att2_k(const u8* __restrict__ h2f,
                                              const float* __restrict__ a2s, const float* __restrict__ a2d,
                                              float* __restrict__ as2, float* __restrict__ ad2, int Nn) {
    int t = blockIdx.x * 256 + threadIdx.x;
    if (t >= Nn * 8) return;
    int n = t >> 3, h = t & 7;
    const u8* hr = h2f + (size_t)n * 320 + h * 40;
    float s1 = 0.f, s2 = 0.f;
#pragma unroll
    for (int b = 0; b < 5; b++) {
        uint2 raw = *reinterpret_cast<const uint2*>(hr + b * 8);
        float h8[8];
        dec8(raw, h8);
#pragma unroll
        for (int j = 0; j < 8; j++) {
            int c = h * 40 + b * 8 + j;
            s1 = fmaf(h8[j], a2s[c], s1);
            s2 = fmaf(h8[j], a2d[c], s2);
        }
    }
    as2[t] = s1;
    ad2[t] = s2;
}

// ---------------- layer-2 aggregation + head-mean + bias + log_softmax ----------------

__global__ __launch_bounds__(256) void agg2_k(const u8* __restrict__ h2f,
                                              const float* __restrict__ as2, const float* __restrict__ ad2,
                                              const int* __restrict__ srcs, const int* __restrict__ rowstart,
                                              const float* __restrict__ b2, float* __restrict__ out, int Nn) {
    __shared__ float smem[4][320];
    int wave = threadIdx.x >> 6, lane = threadIdx.x & 63;
    int n = blockIdx.x * 4 + wave;
    bool active = (n < Nn);
    bool ld = active && (lane < 40);
    const int hl = lane / 5;
    float adl = ld ? ad2[n * 8 + hl] : 0.f;
    float acc[8] = {0, 0, 0, 0, 0, 0, 0, 0};
    float dsum = 0.f;
    if (ld) {
        const size_t loff = (size_t)lane * 8;
        int beg = rowstart[n], end = rowstart[n + 1];
        int i = beg;
        for (; i + 8 <= end; i += 8) {
            int s[8];
#pragma unroll
            for (int u = 0; u < 8; u++) s[u] = srcs[i + u];
            uint2 rw[8];
#pragma unroll
            for (int u = 0; u < 8; u++) rw[u] = *reinterpret_cast<const uint2*>(h2f + (size_t)s[u] * 320 + loff);
            float eg[8];
#pragma unroll
            for (int u = 0; u < 8; u++) eg[u] = as2[s[u] * 8 + hl];
            float p[8];
#pragma unroll
            for (int u = 0; u < 8; u++) { p[u] = lrelu_exp(eg[u] + adl); dsum += p[u]; }
#pragma unroll
            for (int u = 0; u < 8; u++) {
                float hv[8];
                dec8(rw[u], hv);
#pragma unroll
                for (int j = 0; j < 8; j++) acc[j] = fmaf(p[u], hv[j], acc[j]);
            }
        }
        for (; i + 4 <= end; i += 4) {
            int s[4];
#pragma unroll
            for (int u = 0; u < 4; u++) s[u] = srcs[i + u];
            uint2 rw[4];
#pragma unroll
            for (int u = 0; u < 4; u++) rw[u] = *reinterpret_cast<const uint2*>(h2f + (size_t)s[u] * 320 + loff);
#pragma unroll
            for (int u = 0; u < 4; u++) {
                float p = lrelu_exp(as2[s[u] * 8 + hl] + adl);
                dsum += p;
                float hv[8];
                dec8(rw[u], hv);
#pragma unroll
                for (int j = 0; j < 8; j++) acc[j] = fmaf(p, hv[j], acc[j]);
            }
        }
        for (; i < end; i++) {
            int s = srcs[i];
            uint2 raw = *reinterpret_cast<const uint2*>(h2f + (size_t)s * 320 + loff);
            float p = lrelu_exp(as2[s * 8 + hl] + adl);
            dsum += p;
            float hv[8];
            dec8(raw, hv);
#pragma unroll
            for (int j = 0; j < 8; j++) acc[j] = fmaf(p, hv[j], acc[j]);
        }
        float inv = 1.f / (dsum + 1e-16f);
#pragma unroll
        for (int j = 0; j < 8; j++) smem[wave][lane * 8 + j] = acc[j] * inv;
    }
    __syncthreads();
    if (active) {
        float v;
        if (lane < 40) {
            float ssum = 0.f;
#pragma unroll
            for (int h = 0; h < 8; h++) ssum += smem[wave][h * 40 + lane];
            v = ssum * 0.125f + b2[lane];
        } else {
            v = -INFINITY;
        }
        float m = v;
        for (int off = 32; off > 0; off >>= 1) m = fmaxf(m, __shfl_xor(m, off, 64));
        float ex = (lane < 40) ? __expf(v - m) : 0.f;
        float se = ex;
        for (int off = 32; off > 0; off >>= 1) se += __shfl_xor(se, off, 64);
        if (lane < 40) out[(size_t)n * 40 + lane] = v - m - __logf(se);
    }
}

// ---------------- launch ----------------

extern "C" void kernel_launch(void* const* d_in, const int* in_sizes, int n_in,
                              void* d_out, int out_size, void* d_ws, size_t ws_size,
                              hipStream_t stream) {
    const float* x   = (const float*)d_in[0];
    const int*   ei  = (const int*)d_in[1];
    const float* W0  = (const float*)d_in[3];
    const float* a0s = (const float*)d_in[4];
    const float* a0d = (const float*)d_in[5];
    const float* b0  = (const float*)d_in[6];
    const float* W2  = (const float*)d_in[7];
    const float* a2s = (const float*)d_in[8];
    const float* a2d = (const float*)d_in[9];
    const float* b2  = (const float*)d_in[10];
    float* out = (float*)d_out;

    const int Nn = in_sizes[0] / 256;   // 50000
    const int E  = in_sizes[1] / 2;     // 800000
    const int ET = E + Nn;
    const int NB = (Nn + 1023) / 1024;  // scan blocks (<=64)

    size_t off = 0;
    auto carve = [&](size_t bytes) -> void* {
        void* p = (char*)d_ws + off;
        off += (bytes + 255) & ~(size_t)255;
        return p;
    };
    u16*   xb       = (u16*)carve((size_t)Nn * 256 * 2);  // 25.6 MB bf16
    u16*   W0b      = (u16*)carve((size_t)512 * 256 * 2);
    u16*   W2b      = (u16*)carve((size_t)320 * 64 * 2);
    u8*    h1f      = (u8*)carve((size_t)Nn * 512);       // 25.6 MB fp8
    u16*   x1b      = (u16*)carve((size_t)Nn * 64 * 2);
    u8*    h2f      = (u8*)carve((size_t)Nn * 320);       // 16 MB fp8
    float* as1      = (float*)carve((size_t)Nn * 8 * 4);
    float* ad1      = (float*)carve((size_t)Nn * 8 * 4);
    float* as2      = (float*)carve((size_t)Nn * 8 * 4);
    float* ad2      = (float*)carve((size_t)Nn * 8 * 4);
    int*   deg      = (int*)carve((size_t)Nn * 4);
    int*   cursor   = (int*)carve((size_t)Nn * 4);
    int*   rowstart = (int*)carve((size_t)(Nn + 1) * 4);
    int*   srcs     = (int*)carve((size_t)ET * 4);
    int*   incl     = (int*)carve((size_t)Nn * 4);
    int*   bsum     = (int*)carve(64 * 4);
    int*   boff     = (int*)carve(65 * 4);

    hipMemsetAsync(deg, 0, (size_t)Nn * 4, stream);
    hipMemsetAsync(cursor, 0, (size_t)Nn * 4, stream);

    hist_k<<<(ET + 255) / 256, 256, 0, stream>>>(ei, deg, E, Nn);
    scanA_k<<<NB, 1024, 0, stream>>>(deg, incl, bsum, Nn);
    scanB_k<<<1, 64, 0, stream>>>(bsum, boff, NB);
    scanC_k<<<(Nn + 255) / 256, 256, 0, stream>>>(incl, deg, boff, rowstart, Nn, NB);
    scatter_k<<<(ET + 255) / 256, 256, 0, stream>>>(ei, rowstart, cursor, srcs, E, Nn);

    cast_k<<<(Nn * 256 / 4 + 255) / 256, 256, 0, stream>>>(x, xb, Nn * 256);
    cast_k<<<(512 * 256 / 4 + 255) / 256, 256, 0, stream>>>(W0, W0b, 512 * 256);
    cast_k<<<(320 * 64 / 4 + 255) / 256, 256, 0, stream>>>(W2, W2b, 320 * 64);

    // layer 1: GEMM + fused logits, fp8 h1
    gemm_mfma<<<dim3((Nn + 127) / 128, 8), 256, 0, stream>>>(
        xb, W0b, h1f, Nn, 512, 256, a0s, a0d, as1, ad1);
    agg1_k<<<(Nn + 3) / 4, 256, 0, stream>>>(h1f, as1, ad1, srcs, rowstart, b0, x1b, Nn);

    // layer 2: GEMM, fp8 h2
    gemm_mfma<<<dim3((Nn + 127) / 128, 5), 256, 0, stream>>>(
        x1b, W2b, h2f, Nn, 320, 64, nullptr, nullptr, nullptr, nullptr);
    att2_k<<<(Nn * 8 + 255) / 256, 256, 0, stream>>>(h2f, a2s, a2d, as2, ad2, Nn);
    agg2_k<<<(Nn + 3) / 4, 256, 0, stream>>>(h2f, as2, ad2, srcs, rowstart, b2, out, Nn);
}

// Round 9
// 399.630 us; speedup vs baseline: 2.7165x; 1.0117x over previous
//
#include <hip/hip_runtime.h>
#include <hip/hip_bf16.h>
#include <math.h>

// GATNet round 9: scalarized gather addressing in agg kernels
// (readfirstlane on wave-uniform src index -> SGPR-base global_load, no
// per-lane 64-bit addr math; round-8 agg1 showed VALUBusy 60% dominated by
// address VALU). Casts fused 3->1, memsets merged. GEMM unchanged (r8 fix).

#define NEG_SLOPE 0.2f

typedef short v8s __attribute__((ext_vector_type(8)));
typedef float v4f __attribute__((ext_vector_type(4)));
typedef float v2f __attribute__((ext_vector_type(2)));
typedef unsigned short u16;
typedef unsigned int u32;
typedef unsigned char u8;

__device__ __forceinline__ u16 f2bf(float f) {
    union { float f; u32 u; } v; v.f = f;
    u32 r = v.u + 0x7fffu + ((v.u >> 16) & 1u);
    return (u16)(r >> 16);
}
__device__ __forceinline__ float lrelu_exp(float e) {
    e = (e > 0.f) ? e : NEG_SLOPE * e;
    return __expf(e);
}
__device__ __forceinline__ void dec8(uint2 r, float* h) {
    v2f a = __builtin_amdgcn_cvt_pk_f32_fp8(r.x, false);
    v2f b = __builtin_amdgcn_cvt_pk_f32_fp8(r.x, true);
    v2f c = __builtin_amdgcn_cvt_pk_f32_fp8(r.y, false);
    v2f d = __builtin_amdgcn_cvt_pk_f32_fp8(r.y, true);
    h[0] = a.x; h[1] = a.y; h[2] = b.x; h[3] = b.y;
    h[4] = c.x; h[5] = c.y; h[6] = d.x; h[7] = d.y;
}
__device__ __forceinline__ u8 enc8(float v) {
    u32 p = __builtin_amdgcn_cvt_pk_fp8_f32(v, v, 0u, false);
    return (u8)(p & 0xffu);
}

// ---------------- CSR build ----------------

__global__ __launch_bounds__(256) void hist_k(const int* __restrict__ ei, int* __restrict__ deg,
                                              int E, int Nn) {
    int e = blockIdx.x * 256 + threadIdx.x;
    int ET = E + Nn;
    if (e >= ET) return;
    int d = (e < E) ? ei[E + e] : (e - E);
    atomicAdd(&deg[d], 1);
}

__global__ __launch_bounds__(1024) void scanA_k(const int* __restrict__ deg, int* __restrict__ incl,
                                                int* __restrict__ bsum, int n) {
    __shared__ int wsum[16];
    int t = threadIdx.x;
    int i = blockIdx.x * 1024 + t;
    int v = (i < n) ? deg[i] : 0;
    int lane = t & 63, wid = t >> 6;
    int sv = v;
    for (int off = 1; off < 64; off <<= 1) {
        int u = __shfl_up(sv, off, 64);
        if (lane >= off) sv += u;
    }
    if (lane == 63) wsum[wid] = sv;
    __syncthreads();
    if (t < 16) {
        int w = wsum[t];
        for (int off = 1; off < 16; off <<= 1) {
            int u = __shfl_up(w, off, 64);
            if (t >= off) w += u;
        }
        wsum[t] = w;
    }
    __syncthreads();
    int pre = (wid > 0) ? wsum[wid - 1] : 0;
    int inc = pre + sv;
    if (i < n) incl[i] = inc;
    if (t == 1023) bsum[blockIdx.x] = inc;
}

__global__ __launch_bounds__(64) void scanB_k(const int* __restrict__ bsum, int* __restrict__ boff, int B) {
    int t = threadIdx.x;
    int v = (t < B) ? bsum[t] : 0;
    int sv = v;
    for (int off = 1; off < 64; off <<= 1) {
        int u = __shfl_up(sv, off, 64);
        if (t >= off) sv += u;
    }
    if (t < B) boff[t] = sv - v;
    if (t == 63) boff[B] = sv;
}

__global__ __launch_bounds__(256) void scanC_k(const int* __restrict__ incl, const int* __restrict__ deg,
                                               const int* __restrict__ boff, int* __restrict__ rowstart,
                                               int n, int B) {
    int i = blockIdx.x * 256 + threadIdx.x;
    if (i < n) rowstart[i] = boff[i >> 10] + incl[i] - deg[i];
    if (i == 0) rowstart[n] = boff[B];
}

__global__ __launch_bounds__(256) void scatter_k(const int* __restrict__ ei,
                                                 const int* __restrict__ rowstart,
                                                 int* __restrict__ cursor,
                                                 int* __restrict__ srcs, int E, int Nn) {
    int e = blockIdx.x * 256 + threadIdx.x;
    int ET = E + Nn;
    if (e >= ET) return;
    int s, d;
    if (e < E) { s = ei[e]; d = ei[E + e]; }
    else       { s = e - E; d = e - E; }
    int pos = atomicAdd(&cursor[d], 1);
    srcs[rowstart[d] + pos] = s;
}

// ---------------- fused fp32 -> bf16 cast (x, W0, W2 in one dispatch) ----------------

__global__ __launch_bounds__(256) void cast3_k(const float* __restrict__ x, u16* __restrict__ xb, int nx,
                                               const float* __restrict__ W0, u16* __restrict__ W0b, int n0,
                                               const float* __restrict__ W2, u16* __restrict__ W2b, int n2) {
    int i = (blockIdx.x * 256 + threadIdx.x) * 4;
    const float* in; u16* out;
    if (i < nx)            { in = x;  out = xb; }
    else if (i < nx + n0)  { in = W0; out = W0b; i -= nx; }
    else if (i < nx + n0 + n2) { in = W2; out = W2b; i -= nx + n0; }
    else return;
    float4 v = *reinterpret_cast<const float4*>(in + i);
    ushort4 o;
    o.x = f2bf(v.x); o.y = f2bf(v.y); o.z = f2bf(v.z); o.w = f2bf(v.w);
    *reinterpret_cast<ushort4*>(out + i) = o;
}

// ---------------- bf16 MFMA GEMM -> fp8 C ----------------
// 128x64 block tile, BK=64, 4 waves; wave = 32 rows x 64 cols (32 AGPR acc).
// Fused layer-1 logits: block's 64-col slab == one head -> plain store.

__global__ __launch_bounds__(256, 4) void gemm_mfma(const u16* __restrict__ Ab,
                                                    const u16* __restrict__ Bb,
                                                    u8* __restrict__ Cf, int M, int Nc, int K,
                                                    const float* __restrict__ avs_vec,
                                                    const float* __restrict__ avd_vec,
                                                    float* as_out, float* ad_out) {
    __shared__ __align__(16) u8 lds[27648];
    u16 (*As)[72] = reinterpret_cast<u16(*)[72]>(lds);           // 128 rows
    u16 (*Bs)[72] = reinterpret_cast<u16(*)[72]>(lds + 18432);   // 64 rows
    const int t = threadIdx.x;
    const int m0 = blockIdx.x * 128;
    const int n0 = blockIdx.y * 64;
    const int w = t >> 6, lane = t & 63;
    const int wr = w * 32;
    const int q = lane >> 4, l16 = lane & 15;

    v4f acc[2][4];
#pragma unroll
    for (int i = 0; i < 2; i++)
#pragma unroll
        for (int j = 0; j < 4; j++) acc[i][j] = (v4f){0.f, 0.f, 0.f, 0.f};

    for (int kt = 0; kt < K; kt += 64) {
#pragma unroll
        for (int it = 0; it < 4; it++) {
            int c = it * 256 + t;
            int row = c >> 3, col8 = (c & 7) * 8;
            int gm = m0 + row;
            uint4 va = make_uint4(0u, 0u, 0u, 0u);
            if (gm < M) va = *reinterpret_cast<const uint4*>(Ab + (size_t)gm * K + kt + col8);
            *reinterpret_cast<uint4*>(&As[row][col8]) = va;
        }
#pragma unroll
        for (int it = 0; it < 2; it++) {
            int c = it * 256 + t;
            int row = c >> 3, col8 = (c & 7) * 8;
            uint4 vb = *reinterpret_cast<const uint4*>(Bb + (size_t)(n0 + row) * K + kt + col8);
            *reinterpret_cast<uint4*>(&Bs[row][col8]) = vb;
        }
        __syncthreads();
#pragma unroll
        for (int ks = 0; ks < 2; ks++) {
            v8s af[2], bf[4];
#pragma unroll
            for (int i = 0; i < 2; i++)
                af[i] = *reinterpret_cast<const v8s*>(&As[wr + i * 16 + l16][ks * 32 + q * 8]);
#pragma unroll
            for (int j = 0; j < 4; j++)
                bf[j] = *reinterpret_cast<const v8s*>(&Bs[j * 16 + l16][ks * 32 + q * 8]);
#pragma unroll
            for (int i = 0; i < 2; i++)
#pragma unroll
                for (int j = 0; j < 4; j++)
                    acc[i][j] = __builtin_amdgcn_mfma_f32_16x16x32_bf16(af[i], bf[j], acc[i][j], 0, 0, 0);
        }
        __syncthreads();
    }

    const bool do_att = (as_out != nullptr);
    float avs[4], avd[4];
    if (do_att) {
#pragma unroll
        for (int j = 0; j < 4; j++) {
            avs[j] = avs_vec[n0 + j * 16 + l16];
            avd[j] = avd_vec[n0 + j * 16 + l16];
        }
    }
    const int head = n0 >> 6;

    u8* Cs = lds;
#pragma unroll
    for (int i = 0; i < 2; i++) {
#pragma unroll
        for (int r = 0; r < 4; r++) {
            int row = wr + i * 16 + q * 4 + r;
#pragma unroll
            for (int j = 0; j < 4; j++)
                Cs[row * 80 + j * 16 + l16] = enc8(acc[i][j][r]);
            if (do_att) {
                int gm = m0 + row;
                float ps = 0.f, pd = 0.f;
#pragma unroll
                for (int j = 0; j < 4; j++) {
                    float v = acc[i][j][r];
                    ps = fmaf(v, avs[j], ps);
                    pd = fmaf(v, avd[j], pd);
                }
#pragma unroll
                for (int m = 1; m < 16; m <<= 1) {
                    ps += __shfl_xor(ps, m, 64);
                    pd += __shfl_xor(pd, m, 64);
                }
                if (l16 == 0 && gm < M) {
                    as_out[gm * 8 + head] = ps;
                    ad_out[gm * 8 + head] = pd;
                }
            }
        }
    }
    __syncthreads();
#pragma unroll
    for (int it = 0; it < 2; it++) {
        int idx = it * 256 + t;
        int row = idx >> 2, ch = idx & 3;
        int gm = m0 + row;
        if (gm < M)
            *reinterpret_cast<uint4*>(Cf + (size_t)gm * Nc + n0 + ch * 16) =
                *reinterpret_cast<const uint4*>(&Cs[row * 80 + ch * 16]);
    }
}

// ---------------- layer-1 aggregation: wave/dst, scalarized 8-deep fp8 gather ----------------

__global__ __launch_bounds__(256) void agg1_k(const u8* __restrict__ h1f,
                                              const float* __restrict__ as1, const float* __restrict__ ad1,
                                              const int* __restrict__ srcs, const int* __restrict__ rowstart,
                                              const float* __restrict__ b0, u16* __restrict__ x1b, int Nn) {
    int wave = threadIdx.x >> 6, lane = threadIdx.x & 63;
    int n = blockIdx.x * 4 + wave;
    if (n >= Nn) return;
    const int hl = lane >> 3;
    const float adl = ad1[n * 8 + hl];
    const u32 loff = (u32)lane * 8u;
    float acc[8] = {0, 0, 0, 0, 0, 0, 0, 0};
    float dsum = 0.f;
    int beg = rowstart[n], end = rowstart[n + 1];
    int i = beg;
    for (; i + 8 <= end; i += 8) {
        int s[8];
#pragma unroll
        for (int u = 0; u < 8; u++) s[u] = __builtin_amdgcn_readfirstlane(srcs[i + u]);
        uint2 rw[8];
#pragma unroll
        for (int u = 0; u < 8; u++) rw[u] = *reinterpret_cast<const uint2*>(h1f + ((u32)s[u] * 512u + loff));
        float eg[8];
#pragma unroll
        for (int u = 0; u < 8; u++) eg[u] = as1[(u32)s[u] * 8u + hl];
        float p[8];
#pragma unroll
        for (int u = 0; u < 8; u++) { p[u] = lrelu_exp(eg[u] + adl); dsum += p[u]; }
#pragma unroll
        for (int u = 0; u < 8; u++) {
            float hv[8];
            dec8(rw[u], hv);
#pragma unroll
            for (int j = 0; j < 8; j++) acc[j] = fmaf(p[u], hv[j], acc[j]);
        }
    }
    for (; i < end; i++) {
        int s = __builtin_amdgcn_readfirstlane(srcs[i]);
        uint2 raw = *reinterpret_cast<const uint2*>(h1f + ((u32)s * 512u + loff));
        float p = lrelu_exp(as1[(u32)s * 8u + hl] + adl);
        dsum += p;
        float hv[8];
        dec8(raw, hv);
#pragma unroll
        for (int j = 0; j < 8; j++) acc[j] = fmaf(p, hv[j], acc[j]);
    }
    float inv = 1.f / (dsum + 1e-16f);
    float r[8];
#pragma unroll
    for (int j = 0; j < 8; j++) r[j] = acc[j] * inv;
#pragma unroll
    for (int j = 0; j < 8; j++) {
        r[j] += __shfl_xor(r[j], 8, 64);
        r[j] += __shfl_xor(r[j], 16, 64);
        r[j] += __shfl_xor(r[j], 32, 64);
    }
    if (lane < 8) {
        u16 o[8];
#pragma unroll
        for (int j = 0; j < 8; j++) {
            float v = r[j] * 0.125f + b0[lane * 8 + j];
            o[j] = f2bf((v > 0.f) ? v : 0.f);
        }
        *reinterpret_cast<uint4*>(x1b + (size_t)n * 64 + lane * 8) =
            *reinterpret_cast<const uint4*>(o);
    }
}

// ---------------- layer-2 attention logits ----------------

__global__ __launch_bounds__(256) void att2_k(const u8* __restrict__ h2f,
                                              const float* __restrict__ a2s, const float* __restrict__ a2d,
                                              float* __restrict__ as2, float* __restrict__ ad2, int Nn) {
    int t = blockIdx.x * 256 + threadIdx.x;
    if (t >= Nn * 8) return;
    int n = t >> 3, h = t & 7;
    const u8* hr = h2f + (size_t)n * 320 + h * 40;
    float s1 = 0.f, s2 = 0.f;
#pragma unroll
    for (int b = 0; b < 5; b++) {
        uint2 raw = *reinterpret_cast<const uint2*>(hr + b * 8);
        float h8[8];
        dec8(raw, h8);
#pragma unroll
        for (int j = 0; j < 8; j++) {
            int c = h * 40 + b * 8 + j;
            s1 = fmaf(h8[j], a2s[c], s1);
            s2 = fmaf(h8[j], a2d[c], s2);
        }
    }
    as2[t] = s1;
    ad2[t] = s2;
}

// ---------------- layer-2 aggregation + head-mean + bias + log_softmax ----------------

__global__ __launch_bounds__(256) void agg2_k(const u8* __restrict__ h2f,
                                              const float* __restrict__ as2, const float* __restrict__ ad2,
                                              const int* __restrict__ srcs, const int* __restrict__ rowstart,
                                              const float* __restrict__ b2, float* __restrict__ out, int Nn) {
    __shared__ float smem[4][320];
    int wave = threadIdx.x >> 6, lane = threadIdx.x & 63;
    int n = blockIdx.x * 4 + wave;
    bool active = (n < Nn);
    bool ld = active && (lane < 40);
    const int hl = lane / 5;
    float adl = ld ? ad2[n * 8 + hl] : 0.f;
    float acc[8] = {0, 0, 0, 0, 0, 0, 0, 0};
    float dsum = 0.f;
    if (ld) {
        const u32 loff = (u32)lane * 8u;
        int beg = rowstart[n], end = rowstart[n + 1];
        int i = beg;
        for (; i + 8 <= end; i += 8) {
            int s[8];
#pragma unroll
            for (int u = 0; u < 8; u++) s[u] = __builtin_amdgcn_readfirstlane(srcs[i + u]);
            uint2 rw[8];
#pragma unroll
            for (int u = 0; u < 8; u++) rw[u] = *reinterpret_cast<const uint2*>(h2f + ((u32)s[u] * 320u + loff));
            float eg[8];
#pragma unroll
            for (int u = 0; u < 8; u++) eg[u] = as2[(u32)s[u] * 8u + hl];
            float p[8];
#pragma unroll
            for (int u = 0; u < 8; u++) { p[u] = lrelu_exp(eg[u] + adl); dsum += p[u]; }
#pragma unroll
            for (int u = 0; u < 8; u++) {
                float hv[8];
                dec8(rw[u], hv);
#pragma unroll
                for (int j = 0; j < 8; j++) acc[j] = fmaf(p[u], hv[j], acc[j]);
            }
        }
        for (; i < end; i++) {
            int s = __builtin_amdgcn_readfirstlane(srcs[i]);
            uint2 raw = *reinterpret_cast<const uint2*>(h2f + ((u32)s * 320u + loff));
            float p = lrelu_exp(as2[(u32)s * 8u + hl] + adl);
            dsum += p;
            float hv[8];
            dec8(raw, hv);
#pragma unroll
            for (int j = 0; j < 8; j++) acc[j] = fmaf(p, hv[j], acc[j]);
        }
        float inv = 1.f / (dsum + 1e-16f);
#pragma unroll
        for (int j = 0; j < 8; j++) smem[wave][lane * 8 + j] = acc[j] * inv;
    }
    __syncthreads();
    if (active) {
        float v;
        if (lane < 40) {
            float ssum = 0.f;
#pragma unroll
            for (int h = 0; h < 8; h++) ssum += smem[wave][h * 40 + lane];
            v = ssum * 0.125f + b2[lane];
        } else {
            v = -INFINITY;
        }
        float m = v;
        for (int off = 32; off > 0; off >>= 1) m = fmaxf(m, __shfl_xor(m, off, 64));
        float ex = (lane < 40) ? __expf(v - m) : 0.f;
        float se = ex;
        for (int off = 32; off > 0; off >>= 1) se += __shfl_xor(se, off, 64);
        if (lane < 40) out[(size_t)n * 40 + lane] = v - m - __logf(se);
    }
}

// ---------------- launch ----------------

extern "C" void kernel_launch(void* const* d_in, const int* in_sizes, int n_in,
                              void* d_out, int out_size, void* d_ws, size_t ws_size,
                              hipStream_t stream) {
    const float* x   = (const float*)d_in[0];
    const int*   ei  = (const int*)d_in[1];
    const float* W0  = (const float*)d_in[3];
    const float* a0s = (const float*)d_in[4];
    const float* a0d = (const float*)d_in[5];
    const float* b0  = (const float*)d_in[6];
    const float* W2  = (const float*)d_in[7];
    const float* a2s = (const float*)d_in[8];
    const float* a2d = (const float*)d_in[9];
    const float* b2  = (const float*)d_in[10];
    float* out = (float*)d_out;

    const int Nn = in_sizes[0] / 256;   // 50000
    const int E  = in_sizes[1] / 2;     // 800000
    const int ET = E + Nn;
    const int NB = (Nn + 1023) / 1024;  // scan blocks (<=64)

    size_t off = 0;
    auto carve = [&](size_t bytes) -> void* {
        void* p = (char*)d_ws + off;
        off += (bytes + 255) & ~(size_t)255;
        return p;
    };
    u16*   xb       = (u16*)carve((size_t)Nn * 256 * 2);  // 25.6 MB bf16
    u16*   W0b      = (u16*)carve((size_t)512 * 256 * 2);
    u16*   W2b      = (u16*)carve((size_t)320 * 64 * 2);
    u8*    h1f      = (u8*)carve((size_t)Nn * 512);       // 25.6 MB fp8
    u16*   x1b      = (u16*)carve((size_t)Nn * 64 * 2);
    u8*    h2f      = (u8*)carve((size_t)Nn * 320);       // 16 MB fp8
    float* as1      = (float*)carve((size_t)Nn * 8 * 4);
    float* ad1      = (float*)carve((size_t)Nn * 8 * 4);
    float* as2      = (float*)carve((size_t)Nn * 8 * 4);
    float* ad2      = (float*)carve((size_t)Nn * 8 * 4);
    int*   deg      = (int*)carve((size_t)Nn * 4);        // deg+cursor adjacent:
    int*   cursor   = (int*)carve((size_t)Nn * 4);        //   one merged memset
    int*   rowstart = (int*)carve((size_t)(Nn + 1) * 4);
    int*   srcs     = (int*)carve((size_t)ET * 4);
    int*   incl     = (int*)carve((size_t)Nn * 4);
    int*   bsum     = (int*)carve(64 * 4);
    int*   boff     = (int*)carve(65 * 4);

    const size_t degPad = ((size_t)Nn * 4 + 255) & ~(size_t)255;
    hipMemsetAsync(deg, 0, degPad + (size_t)Nn * 4, stream);   // deg + cursor

    hist_k<<<(ET + 255) / 256, 256, 0, stream>>>(ei, deg, E, Nn);
    scanA_k<<<NB, 1024, 0, stream>>>(deg, incl, bsum, Nn);
    scanB_k<<<1, 64, 0, stream>>>(bsum, boff, NB);
    scanC_k<<<(Nn + 255) / 256, 256, 0, stream>>>(incl, deg, boff, rowstart, Nn, NB);
    scatter_k<<<(ET + 255) / 256, 256, 0, stream>>>(ei, rowstart, cursor, srcs, E, Nn);

    const int nx = Nn * 256, n0c = 512 * 256, n2c = 320 * 64;
    cast3_k<<<((nx + n0c + n2c) / 4 + 255) / 256, 256, 0, stream>>>(
        x, xb, nx, W0, W0b, n0c, W2, W2b, n2c);

    // layer 1: GEMM + fused logits, fp8 h1
    gemm_mfma<<<dim3((Nn + 127) / 128, 8), 256, 0, stream>>>(
        xb, W0b, h1f, Nn, 512, 256, a0s, a0d, as1, ad1);
    agg1_k<<<(Nn + 3) / 4, 256, 0, stream>>>(h1f, as1, ad1, srcs, rowstart, b0, x1b, Nn);

    // layer 2: GEMM, fp8 h2
    gemm_mfma<<<dim3((Nn + 127) / 128, 5), 256, 0, stream>>>(
        x1b, W2b, h2f, Nn, 320, 64, nullptr, nullptr, nullptr, nullptr);
    att2_k<<<(Nn * 8 + 255) / 256, 256, 0, stream>>>(h2f, a2s, a2d, as2, ad2, Nn);
    agg2_k<<<(Nn + 3) / 4, 256, 0, stream>>>(h2f, as2, ad2, srcs, rowstart, b2, out, Nn);
}